// Round 1
// baseline (895.291 us; speedup 1.0000x reference)
//
#include <hip/hip_runtime.h>

// ---------- constants ----------
#define T_TOK   8192
#define DMODEL  1024
#define KR      1088      // D + DFE
#define DFE     64
#define DRH     256
#define NE      8
#define DEH     2048
#define MAXROWS 17408
#define MAXMT   136

typedef __bf16 bf16x8 __attribute__((ext_vector_type(8)));
typedef float  f32x4  __attribute__((ext_vector_type(4)));

__device__ __forceinline__ unsigned short f2bf(float f) {
    union { float f; unsigned u; } v; v.f = f;
    unsigned u = v.u;
    u += 0x7FFFu + ((u >> 16) & 1u);   // RNE
    return (unsigned short)(u >> 16);
}
__device__ __forceinline__ float bf2f(unsigned short s) {
    union { unsigned u; float f; } v; v.u = ((unsigned)s) << 16;
    return v.f;
}

#define GLLDS16(gp, lp) \
    __builtin_amdgcn_global_load_lds((const __attribute__((address_space(1))) void*)(gp), \
                                     (__attribute__((address_space(3))) void*)(lp), 16, 0, 0)

// ---------- kernel W: fp32 [E][R][C] -> bf16 [E][C][R] (transpose+convert) ----------
__global__ __launch_bounds__(256) void kT(const float* __restrict__ in,
                                          unsigned short* __restrict__ outT,
                                          int R, int C) {
    __shared__ float tile[32][33];
    const int e = blockIdx.z;
    const float* src = in + (size_t)e * R * C;
    unsigned short* dst = outT + (size_t)e * R * C;
    const int tx = threadIdx.x & 31, ty = threadIdx.x >> 5;
    const int r0 = blockIdx.y * 32, c0 = blockIdx.x * 32;
#pragma unroll
    for (int p = 0; p < 4; ++p)
        tile[ty + p * 8][tx] = src[(size_t)(r0 + ty + p * 8) * C + c0 + tx];
    __syncthreads();
#pragma unroll
    for (int p = 0; p < 4; ++p)
        dst[(size_t)(c0 + ty + p * 8) * R + r0 + tx] = f2bf(tile[tx][ty + p * 8]);
}

// ---------- kernel A: layernorm + stage-feature emb + expert-feature emb ----------
__global__ __launch_bounds__(256) void kA(const float* __restrict__ h, const float* __restrict__ feat,
                                          const float* __restrict__ ln_g, const float* __restrict__ ln_b,
                                          const float* __restrict__ Wsf, const float* __restrict__ bsf,
                                          const float* __restrict__ Wef, const float* __restrict__ bef,
                                          const int* __restrict__ stage_idx, const int* __restrict__ expert_idx,
                                          float* __restrict__ rin, unsigned short* __restrict__ hln,
                                          unsigned short* __restrict__ eemb) {
    const int t = blockIdx.x, tid = threadIdx.x;
    __shared__ float featrow[32];
    __shared__ float red[8];
    if (tid < 32) featrow[tid] = feat[t * 32 + tid];
    const float4 x = *(const float4*)(h + (size_t)t * DMODEL + tid * 4);
    float s = x.x + x.y + x.z + x.w;
#pragma unroll
    for (int off = 32; off > 0; off >>= 1) s += __shfl_xor(s, off);
    if ((tid & 63) == 0) red[tid >> 6] = s;
    __syncthreads();
    const float mean = (red[0] + red[1] + red[2] + red[3]) * (1.0f / 1024.0f);
    const float dx = x.x - mean, dy = x.y - mean, dz = x.z - mean, dw = x.w - mean;
    float q = dx * dx + dy * dy + dz * dz + dw * dw;
#pragma unroll
    for (int off = 32; off > 0; off >>= 1) q += __shfl_xor(q, off);
    if ((tid & 63) == 0) red[4 + (tid >> 6)] = q;
    __syncthreads();
    const float var = (red[4] + red[5] + red[6] + red[7]) * (1.0f / 1024.0f);
    const float inv = 1.0f / sqrtf(var + 1e-5f);
    const float4 g = *(const float4*)(ln_g + tid * 4);
    const float4 b = *(const float4*)(ln_b + tid * 4);
    float4 y;
    y.x = dx * inv * g.x + b.x; y.y = dy * inv * g.y + b.y;
    y.z = dz * inv * g.z + b.z; y.w = dw * inv * g.w + b.w;
    *(float4*)(rin + (size_t)t * KR + tid * 4) = y;
    ushort4 yb; yb.x = f2bf(y.x); yb.y = f2bf(y.y); yb.z = f2bf(y.z); yb.w = f2bf(y.w);
    *(ushort4*)(hln + (size_t)t * DMODEL + tid * 4) = yb;
    if (tid < 64) {  // stage-feature embedding (router input tail), fp32
        float a = bsf[tid];
#pragma unroll
        for (int f = 0; f < 16; ++f) a += featrow[stage_idx[f]] * Wsf[f * DFE + tid];
        rin[(size_t)t * KR + DMODEL + tid] = a;
    }
#pragma unroll
    for (int it = 0; it < 2; ++it) {  // expert-feature embeddings, bf16
        const int idx = it * 256 + tid;
        const int e = idx >> 6, d = idx & 63;
        float a = bef[e * DFE + d];
#pragma unroll
        for (int f = 0; f < 8; ++f) a += featrow[expert_idx[e * 8 + f]] * Wef[(e * 8 + f) * DFE + d];
        eemb[((size_t)t * NE + e) * DFE + d] = f2bf(a);
    }
}

// ---------- kernel B: router GEMM1 fp32 + gelu(tanh) : hr = gelu(rin @ Wr1 + br1) ----------
__global__ __launch_bounds__(256) void kB(const float* __restrict__ rin, const float* __restrict__ Wr1,
                                          const float* __restrict__ br1, float* __restrict__ hr) {
    __shared__ float As[16][72];   // [k][m], padded
    __shared__ float Bs[16][64];   // [k][n]
    const int tid = threadIdx.x;
    const int m0 = blockIdx.y * 64, n0 = blockIdx.x * 64;
    const int tm = tid & 15, tn = tid >> 4;
    const int ar = tid >> 2, ak = (tid & 3) * 4;
    const int bk = tid >> 4, bn = (tid & 15) * 4;
    float acc[4][4] = {};
    for (int k0 = 0; k0 < KR; k0 += 16) {
        const float4 av = *(const float4*)(rin + (size_t)(m0 + ar) * KR + k0 + ak);
        const float4 bv = *(const float4*)(Wr1 + (size_t)(k0 + bk) * DRH + n0 + bn);
        __syncthreads();
        As[ak + 0][ar] = av.x; As[ak + 1][ar] = av.y; As[ak + 2][ar] = av.z; As[ak + 3][ar] = av.w;
        *(float4*)&Bs[bk][bn] = bv;
        __syncthreads();
#pragma unroll
        for (int kk = 0; kk < 16; ++kk) {
            const float4 a = *(const float4*)&As[kk][tm * 4];
            const float4 bq = *(const float4*)&Bs[kk][tn * 4];
            acc[0][0] += a.x * bq.x; acc[0][1] += a.x * bq.y; acc[0][2] += a.x * bq.z; acc[0][3] += a.x * bq.w;
            acc[1][0] += a.y * bq.x; acc[1][1] += a.y * bq.y; acc[1][2] += a.y * bq.z; acc[1][3] += a.y * bq.w;
            acc[2][0] += a.z * bq.x; acc[2][1] += a.z * bq.y; acc[2][2] += a.z * bq.z; acc[2][3] += a.z * bq.w;
            acc[3][0] += a.w * bq.x; acc[3][1] += a.w * bq.y; acc[3][2] += a.w * bq.z; acc[3][3] += a.w * bq.w;
        }
    }
#pragma unroll
    for (int i = 0; i < 4; ++i) {
        const int row = m0 + tm * 4 + i;
#pragma unroll
        for (int j = 0; j < 4; ++j) {
            const int col = n0 + tn * 4 + j;
            const float v = acc[i][j] + br1[col];
            const float u = 0.7978845608028654f * (v + 0.044715f * v * v * v);
            hr[(size_t)row * DRH + col] = 0.5f * v * (1.0f + tanhf(u));
        }
    }
}

// ---------- kernel C: router head + top-2 softmax gating + expert counts ----------
__global__ __launch_bounds__(256) void kC(const float* __restrict__ hr, const float* __restrict__ Wr2,
                                          const float* __restrict__ br2, int* __restrict__ top_e,
                                          float* __restrict__ top_w, int* __restrict__ counts) {
    const int tid = threadIdx.x, lane = tid & 63, w = tid >> 6;
    const int t = blockIdx.x * 4 + w;
    float acc[8] = {};
#pragma unroll
    for (int r = 0; r < 4; ++r) {
        const int k = r * 64 + lane;
        const float hv = hr[(size_t)t * DRH + k];
        const float4 w0 = *(const float4*)(Wr2 + k * 8);
        const float4 w1 = *(const float4*)(Wr2 + k * 8 + 4);
        acc[0] += hv * w0.x; acc[1] += hv * w0.y; acc[2] += hv * w0.z; acc[3] += hv * w0.w;
        acc[4] += hv * w1.x; acc[5] += hv * w1.y; acc[6] += hv * w1.z; acc[7] += hv * w1.w;
    }
#pragma unroll
    for (int off = 32; off > 0; off >>= 1)
#pragma unroll
        for (int j = 0; j < 8; ++j) acc[j] += __shfl_xor(acc[j], off);
    if (lane == 0) {
#pragma unroll
        for (int j = 0; j < 8; ++j) acc[j] += br2[j];
        float v1 = -1e30f; int i1 = 0;
#pragma unroll
        for (int j = 0; j < 8; ++j) if (acc[j] > v1) { v1 = acc[j]; i1 = j; }
        float v2 = -1e30f; int i2 = 0;
#pragma unroll
        for (int j = 0; j < 8; ++j) if (j != i1 && acc[j] > v2) { v2 = acc[j]; i2 = j; }
        const float e2 = expf(v2 - v1);
        const float inv = 1.0f / (1.0f + e2);
        top_e[2 * t] = i1; top_e[2 * t + 1] = i2;
        top_w[2 * t] = inv; top_w[2 * t + 1] = e2 * inv;
        atomicAdd(&counts[i1], 1); atomicAdd(&counts[i2], 1);
    }
}

// ---------- kernel D: padded prefix sum over expert counts ----------
__global__ void kD(const int* __restrict__ counts, int* __restrict__ offsets) {
    if (threadIdx.x == 0) {
        int off = 0;
        for (int e = 0; e < NE; ++e) { offsets[e] = off; off += (counts[e] + 127) & ~127; }
        offsets[NE] = off;
    }
}

// ---------- kernel E: scatter token->row assignments ----------
__global__ __launch_bounds__(256) void kE(const int* __restrict__ top_e, const int* __restrict__ offsets,
                                          int* __restrict__ fill, int* __restrict__ rowtok,
                                          int* __restrict__ tok2row) {
    const int t = blockIdx.x * 256 + threadIdx.x;
#pragma unroll
    for (int k = 0; k < 2; ++k) {
        const int e = top_e[2 * t + k];
        const int pos = atomicAdd(&fill[e], 1);
        const int row = offsets[e] + pos;
        rowtok[row] = t;
        tok2row[2 * t + k] = row;
    }
}

// ---------- kernel F: gather per-assignment A rows [hln | eemb(e)] ----------
__global__ __launch_bounds__(128) void kF(const unsigned short* __restrict__ hln,
                                          const unsigned short* __restrict__ eemb,
                                          const int* __restrict__ rowtok, const int* __restrict__ offsets,
                                          unsigned short* __restrict__ xin) {
    const int row = blockIdx.x;
    if (row >= offsets[NE]) return;
    const int tid = threadIdx.x;
    const int t = rowtok[row];
    uint4* dst = (uint4*)(xin + (size_t)row * KR);
    if (t < 0) {
        const uint4 z = {0u, 0u, 0u, 0u};
        dst[tid] = z;
        if (tid < 8) dst[128 + tid] = z;
    } else {
        int e = 0;
        while (row >= offsets[e + 1]) ++e;
        dst[tid] = ((const uint4*)(hln + (size_t)t * DMODEL))[tid];
        if (tid < 8) dst[128 + tid] = ((const uint4*)(eemb + ((size_t)t * NE + e) * DFE))[tid];
    }
}

// ---------- expert GEMM1: hh = gelu(xin @ We1[e] + be1[e]) , bf16 MFMA ----------
__global__ __launch_bounds__(256) void gemm1(const unsigned short* __restrict__ A,
                                             const unsigned short* __restrict__ BT,
                                             const float* __restrict__ be1,
                                             unsigned short* __restrict__ hh,
                                             const int* __restrict__ offsets) {
    const int m_base = blockIdx.y * 128;
    if (m_base >= offsets[NE]) return;
    int e = 0;
    while (m_base >= offsets[e + 1]) ++e;
    const int n_base = blockIdx.x * 128;
    __shared__ unsigned short As[128 * 64];
    __shared__ unsigned short Bs[128 * 64];
    const int tid = threadIdx.x, lane = tid & 63, wave = tid >> 6;
    const int wm = (wave & 1) * 64, wn = (wave >> 1) * 64;
    const int l16 = lane & 15, quad = lane >> 4;
    f32x4 acc[4][4];
#pragma unroll
    for (int mi = 0; mi < 4; ++mi)
#pragma unroll
        for (int ni = 0; ni < 4; ++ni) { acc[mi][ni].x = 0.f; acc[mi][ni].y = 0.f; acc[mi][ni].z = 0.f; acc[mi][ni].w = 0.f; }
    const unsigned short* Ap = A + (size_t)m_base * KR;
    const unsigned short* Bp = BT + ((size_t)e * DEH + n_base) * KR;
    for (int k0 = 0; k0 < KR; k0 += 64) {
#pragma unroll
        for (int i = 0; i < 4; ++i) {
            const int ch = i * 256 + tid;
            const int r = ch >> 3, c = ch & 7;
            GLLDS16(Ap + (size_t)r * KR + k0 + c * 8, As + (i * 256 + wave * 64) * 8);
            GLLDS16(Bp + (size_t)r * KR + k0 + c * 8, Bs + (i * 256 + wave * 64) * 8);
        }
        __syncthreads();
#pragma unroll
        for (int kc = 0; kc < 2; ++kc) {
            bf16x8 af[4], bfr[4];
#pragma unroll
            for (int mi = 0; mi < 4; ++mi)
                af[mi] = *(const bf16x8*)(As + (wm + mi * 16 + l16) * 64 + kc * 32 + quad * 8);
#pragma unroll
            for (int ni = 0; ni < 4; ++ni)
                bfr[ni] = *(const bf16x8*)(Bs + (wn + ni * 16 + l16) * 64 + kc * 32 + quad * 8);
#pragma unroll
            for (int mi = 0; mi < 4; ++mi)
#pragma unroll
                for (int ni = 0; ni < 4; ++ni)
                    acc[mi][ni] = __builtin_amdgcn_mfma_f32_16x16x32_bf16(af[mi], bfr[ni], acc[mi][ni], 0, 0, 0);
        }
        __syncthreads();
    }
#pragma unroll
    for (int ni = 0; ni < 4; ++ni) {
        const int col = n_base + wn + ni * 16 + l16;
        const float bias = be1[e * DEH + col];
#pragma unroll
        for (int mi = 0; mi < 4; ++mi) {
            const int row = m_base + wm + mi * 16 + quad * 4;
#pragma unroll
            for (int r = 0; r < 4; ++r) {
                const float v = acc[mi][ni][r] + bias;
                const float gl = v / (1.0f + __expf(-1.5957691216057308f * (v + 0.044715f * v * v * v)));
                hh[(size_t)(row + r) * DEH + col] = f2bf(gl);
            }
        }
    }
}

// ---------- expert GEMM2: eo = hh @ We2[e] + be2[e] , bf16 MFMA ----------
__global__ __launch_bounds__(256) void gemm2(const unsigned short* __restrict__ A,
                                             const unsigned short* __restrict__ BT,
                                             const float* __restrict__ be2,
                                             unsigned short* __restrict__ eo,
                                             const int* __restrict__ offsets) {
    const int m_base = blockIdx.y * 128;
    if (m_base >= offsets[NE]) return;
    int e = 0;
    while (m_base >= offsets[e + 1]) ++e;
    const int n_base = blockIdx.x * 128;
    __shared__ unsigned short As[128 * 64];
    __shared__ unsigned short Bs[128 * 64];
    const int tid = threadIdx.x, lane = tid & 63, wave = tid >> 6;
    const int wm = (wave & 1) * 64, wn = (wave >> 1) * 64;
    const int l16 = lane & 15, quad = lane >> 4;
    f32x4 acc[4][4];
#pragma unroll
    for (int mi = 0; mi < 4; ++mi)
#pragma unroll
        for (int ni = 0; ni < 4; ++ni) { acc[mi][ni].x = 0.f; acc[mi][ni].y = 0.f; acc[mi][ni].z = 0.f; acc[mi][ni].w = 0.f; }
    const unsigned short* Ap = A + (size_t)m_base * DEH;
    const unsigned short* Bp = BT + ((size_t)e * DMODEL + n_base) * DEH;
    for (int k0 = 0; k0 < DEH; k0 += 64) {
#pragma unroll
        for (int i = 0; i < 4; ++i) {
            const int ch = i * 256 + tid;
            const int r = ch >> 3, c = ch & 7;
            GLLDS16(Ap + (size_t)r * DEH + k0 + c * 8, As + (i * 256 + wave * 64) * 8);
            GLLDS16(Bp + (size_t)r * DEH + k0 + c * 8, Bs + (i * 256 + wave * 64) * 8);
        }
        __syncthreads();
#pragma unroll
        for (int kc = 0; kc < 2; ++kc) {
            bf16x8 af[4], bfr[4];
#pragma unroll
            for (int mi = 0; mi < 4; ++mi)
                af[mi] = *(const bf16x8*)(As + (wm + mi * 16 + l16) * 64 + kc * 32 + quad * 8);
#pragma unroll
            for (int ni = 0; ni < 4; ++ni)
                bfr[ni] = *(const bf16x8*)(Bs + (wn + ni * 16 + l16) * 64 + kc * 32 + quad * 8);
#pragma unroll
            for (int mi = 0; mi < 4; ++mi)
#pragma unroll
                for (int ni = 0; ni < 4; ++ni)
                    acc[mi][ni] = __builtin_amdgcn_mfma_f32_16x16x32_bf16(af[mi], bfr[ni], acc[mi][ni], 0, 0, 0);
        }
        __syncthreads();
    }
#pragma unroll
    for (int ni = 0; ni < 4; ++ni) {
        const int col = n_base + wn + ni * 16 + l16;
        const float bias = be2[e * DMODEL + col];
#pragma unroll
        for (int mi = 0; mi < 4; ++mi) {
            const int row = m_base + wm + mi * 16 + quad * 4;
#pragma unroll
            for (int r = 0; r < 4; ++r)
                eo[(size_t)(row + r) * DMODEL + col] = f2bf(acc[mi][ni][r] + bias);
        }
    }
}

// ---------- combine: out = h + w0*eo[r0] + w1*eo[r1] ----------
__global__ __launch_bounds__(256) void kComb(const float* __restrict__ h, const unsigned short* __restrict__ eo,
                                             const int* __restrict__ tok2row, const float* __restrict__ top_w,
                                             float* __restrict__ out) {
    const int t = blockIdx.x, tid = threadIdx.x;
    const int r0 = tok2row[2 * t], r1 = tok2row[2 * t + 1];
    const float w0 = top_w[2 * t], w1 = top_w[2 * t + 1];
    const float4 hv = *(const float4*)(h + (size_t)t * DMODEL + tid * 4);
    const ushort4 a = *(const ushort4*)(eo + (size_t)r0 * DMODEL + tid * 4);
    const ushort4 b = *(const ushort4*)(eo + (size_t)r1 * DMODEL + tid * 4);
    float4 o;
    o.x = hv.x + w0 * bf2f(a.x) + w1 * bf2f(b.x);
    o.y = hv.y + w0 * bf2f(a.y) + w1 * bf2f(b.y);
    o.z = hv.z + w0 * bf2f(a.z) + w1 * bf2f(b.z);
    o.w = hv.w + w0 * bf2f(a.w) + w1 * bf2f(b.w);
    *(float4*)(out + (size_t)t * DMODEL + tid * 4) = o;
}

extern "C" void kernel_launch(void* const* d_in, const int* in_sizes, int n_in,
                              void* d_out, int out_size, void* d_ws, size_t ws_size,
                              hipStream_t stream) {
    const float* h    = (const float*)d_in[0];
    const float* feat = (const float*)d_in[1];
    const float* ln_g = (const float*)d_in[2];
    const float* ln_b = (const float*)d_in[3];
    const float* Wsf  = (const float*)d_in[4];
    const float* bsf  = (const float*)d_in[5];
    const float* Wr1  = (const float*)d_in[6];
    const float* br1  = (const float*)d_in[7];
    const float* Wr2  = (const float*)d_in[8];
    const float* br2  = (const float*)d_in[9];
    const float* Wef  = (const float*)d_in[10];
    const float* bef  = (const float*)d_in[11];
    const float* We1  = (const float*)d_in[12];
    const float* be1  = (const float*)d_in[13];
    const float* We2  = (const float*)d_in[14];
    const float* be2  = (const float*)d_in[15];
    const int* stage_idx  = (const int*)d_in[16];
    const int* expert_idx = (const int*)d_in[17];
    float* out = (float*)d_out;

    char* ws = (char*)d_ws;
    // region R0 [0, 75497472): router-phase buffers; hh aliases it afterwards
    float*          rin  = (float*)(ws + 0);                       // 8192*1088*4  = 35651584
    unsigned short* hln  = (unsigned short*)(ws + 35651584);       // 8192*1024*2  = 16777216
    unsigned short* eemb = (unsigned short*)(ws + 52428800);       // 8192*8*64*2  = 8388608
    float*          hr   = (float*)(ws + 60817408);                // 8192*256*4   = 8388608
    unsigned short* hh   = (unsigned short*)(ws + 0);              // alias: 17408*2048*2 = 71303168
    unsigned short* xin  = (unsigned short*)(ws + 75497472);       // 17408*1088*2 = 37879808
    unsigned short* eo   = (unsigned short*)(ws + 75497472);       // alias: 17408*1024*2 = 35651584
    unsigned short* We1T = (unsigned short*)(ws + 113377280);      // 35651584
    unsigned short* We2T = (unsigned short*)(ws + 149028864);      // 33554432
    int*   top_e   = (int*)(ws + 182583296);
    float* top_w   = (float*)(ws + 182648832);
    int*   tok2row = (int*)(ws + 182714368);
    int*   rowtok  = (int*)(ws + 182779904);
    int*   counts  = (int*)(ws + 182849536);
    int*   fill    = (int*)(ws + 182849600);
    int*   offsets = (int*)(ws + 182849664);
    if (ws_size < 182849728) return;

    hipMemsetAsync(counts, 0, 128, stream);                  // counts + fill
    hipMemsetAsync(rowtok, 0xFF, MAXROWS * 4, stream);       // rowtok = -1

    kT<<<dim3(64, 34, 8), 256, 0, stream>>>(We1, We1T, KR, DEH);
    kT<<<dim3(32, 64, 8), 256, 0, stream>>>(We2, We2T, DEH, DMODEL);
    kA<<<T_TOK, 256, 0, stream>>>(h, feat, ln_g, ln_b, Wsf, bsf, Wef, bef,
                                  stage_idx, expert_idx, rin, hln, eemb);
    kB<<<dim3(DRH / 64, T_TOK / 64), 256, 0, stream>>>(rin, Wr1, br1, hr);
    kC<<<T_TOK / 4, 256, 0, stream>>>(hr, Wr2, br2, top_e, top_w, counts);
    kD<<<1, 64, 0, stream>>>(counts, offsets);
    kE<<<T_TOK / 256, 256, 0, stream>>>(top_e, offsets, fill, rowtok, tok2row);
    kF<<<MAXROWS, 128, 0, stream>>>(hln, eemb, rowtok, offsets, xin);
    gemm1<<<dim3(DEH / 128, MAXMT), 256, 0, stream>>>(xin, We1T, be1, hh, offsets);
    gemm2<<<dim3(DMODEL / 128, MAXMT), 256, 0, stream>>>(hh, We2T, be2, eo, offsets);
    kComb<<<T_TOK, 256, 0, stream>>>(h, eo, tok2row, top_w, out);
}

// Round 2
// 636.785 us; speedup vs baseline: 1.4060x; 1.4060x over previous
//
#include <hip/hip_runtime.h>

// ---------- constants ----------
#define T_TOK   8192
#define DMODEL  1024
#define KR      1088      // D + DFE
#define DFE     64
#define DRH     256
#define NE      8
#define DEH     2048
#define MAXROWS 17408
#define MAXMT   136

typedef __bf16 bf16x8 __attribute__((ext_vector_type(8)));
typedef float  f32x4  __attribute__((ext_vector_type(4)));

__device__ __forceinline__ unsigned short f2bf(float f) {
    union { float f; unsigned u; } v; v.f = f;
    unsigned u = v.u;
    u += 0x7FFFu + ((u >> 16) & 1u);   // RNE
    return (unsigned short)(u >> 16);
}
__device__ __forceinline__ float bf2f(unsigned short s) {
    union { unsigned u; float f; } v; v.u = ((unsigned)s) << 16;
    return v.f;
}

#define GLLDS16(gp, lp) \
    __builtin_amdgcn_global_load_lds((const __attribute__((address_space(1))) void*)(gp), \
                                     (__attribute__((address_space(3))) void*)(lp), 16, 0, 0)

// ---------- kernel W: fp32 [E][R][C] -> bf16 [E][C][R] (transpose+convert) ----------
__global__ __launch_bounds__(256) void kT(const float* __restrict__ in,
                                          unsigned short* __restrict__ outT,
                                          int R, int C) {
    __shared__ float tile[32][33];
    const int e = blockIdx.z;
    const float* src = in + (size_t)e * R * C;
    unsigned short* dst = outT + (size_t)e * R * C;
    const int tx = threadIdx.x & 31, ty = threadIdx.x >> 5;
    const int r0 = blockIdx.y * 32, c0 = blockIdx.x * 32;
#pragma unroll
    for (int p = 0; p < 4; ++p)
        tile[ty + p * 8][tx] = src[(size_t)(r0 + ty + p * 8) * C + c0 + tx];
    __syncthreads();
#pragma unroll
    for (int p = 0; p < 4; ++p)
        dst[(size_t)(c0 + ty + p * 8) * R + r0 + tx] = f2bf(tile[tx][ty + p * 8]);
}

// ---------- kernel A: layernorm + stage-feature emb + expert-feature emb ----------
__global__ __launch_bounds__(256) void kA(const float* __restrict__ h, const float* __restrict__ feat,
                                          const float* __restrict__ ln_g, const float* __restrict__ ln_b,
                                          const float* __restrict__ Wsf, const float* __restrict__ bsf,
                                          const float* __restrict__ Wef, const float* __restrict__ bef,
                                          const int* __restrict__ stage_idx, const int* __restrict__ expert_idx,
                                          float* __restrict__ rin, unsigned short* __restrict__ hln,
                                          unsigned short* __restrict__ eemb) {
    const int t = blockIdx.x, tid = threadIdx.x;
    __shared__ float featrow[32];
    __shared__ float red[8];
    if (tid < 32) featrow[tid] = feat[t * 32 + tid];
    const float4 x = *(const float4*)(h + (size_t)t * DMODEL + tid * 4);
    float s = x.x + x.y + x.z + x.w;
#pragma unroll
    for (int off = 32; off > 0; off >>= 1) s += __shfl_xor(s, off);
    if ((tid & 63) == 0) red[tid >> 6] = s;
    __syncthreads();
    const float mean = (red[0] + red[1] + red[2] + red[3]) * (1.0f / 1024.0f);
    const float dx = x.x - mean, dy = x.y - mean, dz = x.z - mean, dw = x.w - mean;
    float q = dx * dx + dy * dy + dz * dz + dw * dw;
#pragma unroll
    for (int off = 32; off > 0; off >>= 1) q += __shfl_xor(q, off);
    if ((tid & 63) == 0) red[4 + (tid >> 6)] = q;
    __syncthreads();
    const float var = (red[4] + red[5] + red[6] + red[7]) * (1.0f / 1024.0f);
    const float inv = 1.0f / sqrtf(var + 1e-5f);
    const float4 g = *(const float4*)(ln_g + tid * 4);
    const float4 b = *(const float4*)(ln_b + tid * 4);
    float4 y;
    y.x = dx * inv * g.x + b.x; y.y = dy * inv * g.y + b.y;
    y.z = dz * inv * g.z + b.z; y.w = dw * inv * g.w + b.w;
    *(float4*)(rin + (size_t)t * KR + tid * 4) = y;
    ushort4 yb; yb.x = f2bf(y.x); yb.y = f2bf(y.y); yb.z = f2bf(y.z); yb.w = f2bf(y.w);
    *(ushort4*)(hln + (size_t)t * DMODEL + tid * 4) = yb;
    if (tid < 64) {  // stage-feature embedding (router input tail), fp32
        float a = bsf[tid];
#pragma unroll
        for (int f = 0; f < 16; ++f) a += featrow[stage_idx[f]] * Wsf[f * DFE + tid];
        rin[(size_t)t * KR + DMODEL + tid] = a;
    }
#pragma unroll
    for (int it = 0; it < 2; ++it) {  // expert-feature embeddings, bf16
        const int idx = it * 256 + tid;
        const int e = idx >> 6, d = idx & 63;
        float a = bef[e * DFE + d];
#pragma unroll
        for (int f = 0; f < 8; ++f) a += featrow[expert_idx[e * 8 + f]] * Wef[(e * 8 + f) * DFE + d];
        eemb[((size_t)t * NE + e) * DFE + d] = f2bf(a);
    }
}

// ---------- kernel B: router GEMM1 fp32 + gelu(tanh) : hr = gelu(rin @ Wr1 + br1) ----------
__global__ __launch_bounds__(256) void kB(const float* __restrict__ rin, const float* __restrict__ Wr1,
                                          const float* __restrict__ br1, float* __restrict__ hr) {
    __shared__ float As[16][72];   // [k][m], padded
    __shared__ float Bs[16][64];   // [k][n]
    const int tid = threadIdx.x;
    const int m0 = blockIdx.y * 64, n0 = blockIdx.x * 64;
    const int tm = tid & 15, tn = tid >> 4;
    const int ar = tid >> 2, ak = (tid & 3) * 4;
    const int bk = tid >> 4, bn = (tid & 15) * 4;
    float acc[4][4] = {};
    for (int k0 = 0; k0 < KR; k0 += 16) {
        const float4 av = *(const float4*)(rin + (size_t)(m0 + ar) * KR + k0 + ak);
        const float4 bv = *(const float4*)(Wr1 + (size_t)(k0 + bk) * DRH + n0 + bn);
        __syncthreads();
        As[ak + 0][ar] = av.x; As[ak + 1][ar] = av.y; As[ak + 2][ar] = av.z; As[ak + 3][ar] = av.w;
        *(float4*)&Bs[bk][bn] = bv;
        __syncthreads();
#pragma unroll
        for (int kk = 0; kk < 16; ++kk) {
            const float4 a = *(const float4*)&As[kk][tm * 4];
            const float4 bq = *(const float4*)&Bs[kk][tn * 4];
            acc[0][0] += a.x * bq.x; acc[0][1] += a.x * bq.y; acc[0][2] += a.x * bq.z; acc[0][3] += a.x * bq.w;
            acc[1][0] += a.y * bq.x; acc[1][1] += a.y * bq.y; acc[1][2] += a.y * bq.z; acc[1][3] += a.y * bq.w;
            acc[2][0] += a.z * bq.x; acc[2][1] += a.z * bq.y; acc[2][2] += a.z * bq.z; acc[2][3] += a.z * bq.w;
            acc[3][0] += a.w * bq.x; acc[3][1] += a.w * bq.y; acc[3][2] += a.w * bq.z; acc[3][3] += a.w * bq.w;
        }
    }
#pragma unroll
    for (int i = 0; i < 4; ++i) {
        const int row = m0 + tm * 4 + i;
#pragma unroll
        for (int j = 0; j < 4; ++j) {
            const int col = n0 + tn * 4 + j;
            const float v = acc[i][j] + br1[col];
            const float u = 0.7978845608028654f * (v + 0.044715f * v * v * v);
            hr[(size_t)row * DRH + col] = 0.5f * v * (1.0f + tanhf(u));
        }
    }
}

// ---------- kernel C: router head + top-2 softmax gating (NO atomics) ----------
__global__ __launch_bounds__(256) void kC(const float* __restrict__ hr, const float* __restrict__ Wr2,
                                          const float* __restrict__ br2, int* __restrict__ top_e,
                                          float* __restrict__ top_w) {
    const int tid = threadIdx.x, lane = tid & 63, w = tid >> 6;
    const int t = blockIdx.x * 4 + w;
    float acc[8] = {};
#pragma unroll
    for (int r = 0; r < 4; ++r) {
        const int k = r * 64 + lane;
        const float hv = hr[(size_t)t * DRH + k];
        const float4 w0 = *(const float4*)(Wr2 + k * 8);
        const float4 w1 = *(const float4*)(Wr2 + k * 8 + 4);
        acc[0] += hv * w0.x; acc[1] += hv * w0.y; acc[2] += hv * w0.z; acc[3] += hv * w0.w;
        acc[4] += hv * w1.x; acc[5] += hv * w1.y; acc[6] += hv * w1.z; acc[7] += hv * w1.w;
    }
#pragma unroll
    for (int off = 32; off > 0; off >>= 1)
#pragma unroll
        for (int j = 0; j < 8; ++j) acc[j] += __shfl_xor(acc[j], off);
    if (lane == 0) {
#pragma unroll
        for (int j = 0; j < 8; ++j) acc[j] += br2[j];
        float v1 = -1e30f; int i1 = 0;
#pragma unroll
        for (int j = 0; j < 8; ++j) if (acc[j] > v1) { v1 = acc[j]; i1 = j; }
        float v2 = -1e30f; int i2 = 0;
#pragma unroll
        for (int j = 0; j < 8; ++j) if (j != i1 && acc[j] > v2) { v2 = acc[j]; i2 = j; }
        const float e2 = expf(v2 - v1);
        const float inv = 1.0f / (1.0f + e2);
        top_e[2 * t] = i1; top_e[2 * t + 1] = i2;
        top_w[2 * t] = inv; top_w[2 * t + 1] = e2 * inv;
    }
}

// ---------- kernel Cnt: LDS-privatized expert histogram (256 global atomics total) ----------
__global__ __launch_bounds__(256) void kCnt(const int* __restrict__ top_e, int* __restrict__ counts) {
    __shared__ int lc[NE];
    const int tid = threadIdx.x;
    if (tid < NE) lc[tid] = 0;
    __syncthreads();
    const int t = blockIdx.x * 256 + tid;
    atomicAdd(&lc[top_e[2 * t]], 1);
    atomicAdd(&lc[top_e[2 * t + 1]], 1);
    __syncthreads();
    if (tid < NE) atomicAdd(&counts[tid], lc[tid]);
}

// ---------- kernel D: padded prefix sum over expert counts ----------
__global__ void kD(const int* __restrict__ counts, int* __restrict__ offsets) {
    if (threadIdx.x == 0) {
        int off = 0;
        for (int e = 0; e < NE; ++e) { offsets[e] = off; off += (counts[e] + 127) & ~127; }
        offsets[NE] = off;
    }
}

// ---------- kernel E: scatter token->row, block-aggregated (256 global atomics total) ----------
__global__ __launch_bounds__(256) void kE(const int* __restrict__ top_e, const int* __restrict__ offsets,
                                          int* __restrict__ fill, int* __restrict__ rowtok,
                                          int* __restrict__ tok2row) {
    __shared__ int lc[NE], lbase[NE], lpos[NE];
    const int tid = threadIdx.x;
    if (tid < NE) { lc[tid] = 0; lpos[tid] = 0; }
    __syncthreads();
    const int t = blockIdx.x * 256 + tid;
    const int e0 = top_e[2 * t], e1 = top_e[2 * t + 1];
    atomicAdd(&lc[e0], 1);
    atomicAdd(&lc[e1], 1);
    __syncthreads();
    if (tid < NE) lbase[tid] = atomicAdd(&fill[tid], lc[tid]);
    __syncthreads();
    const int p0 = atomicAdd(&lpos[e0], 1);
    const int p1 = atomicAdd(&lpos[e1], 1);
    const int r0 = offsets[e0] + lbase[e0] + p0;
    const int r1 = offsets[e1] + lbase[e1] + p1;
    rowtok[r0] = t; rowtok[r1] = t;
    tok2row[2 * t] = r0; tok2row[2 * t + 1] = r1;
}

// ---------- kernel F: gather per-assignment A rows [hln | eemb(e)] ----------
__global__ __launch_bounds__(128) void kF(const unsigned short* __restrict__ hln,
                                          const unsigned short* __restrict__ eemb,
                                          const int* __restrict__ rowtok, const int* __restrict__ offsets,
                                          unsigned short* __restrict__ xin) {
    const int row = blockIdx.x;
    if (row >= offsets[NE]) return;
    const int tid = threadIdx.x;
    const int t = rowtok[row];
    uint4* dst = (uint4*)(xin + (size_t)row * KR);
    if (t < 0) {
        const uint4 z = {0u, 0u, 0u, 0u};
        dst[tid] = z;
        if (tid < 8) dst[128 + tid] = z;
    } else {
        int e = 0;
        while (row >= offsets[e + 1]) ++e;
        dst[tid] = ((const uint4*)(hln + (size_t)t * DMODEL))[tid];
        if (tid < 8) dst[128 + tid] = ((const uint4*)(eemb + ((size_t)t * NE + e) * DFE))[tid];
    }
}

// ---------- expert GEMM1: hh = gelu(xin @ We1[e] + be1[e]) , bf16 MFMA ----------
__global__ __launch_bounds__(256) void gemm1(const unsigned short* __restrict__ A,
                                             const unsigned short* __restrict__ BT,
                                             const float* __restrict__ be1,
                                             unsigned short* __restrict__ hh,
                                             const int* __restrict__ offsets) {
    const int m_base = blockIdx.y * 128;
    if (m_base >= offsets[NE]) return;
    int e = 0;
    while (m_base >= offsets[e + 1]) ++e;
    const int n_base = blockIdx.x * 128;
    __shared__ unsigned short As[128 * 64];
    __shared__ unsigned short Bs[128 * 64];
    const int tid = threadIdx.x, lane = tid & 63, wave = tid >> 6;
    const int wm = (wave & 1) * 64, wn = (wave >> 1) * 64;
    const int l16 = lane & 15, quad = lane >> 4;
    f32x4 acc[4][4];
#pragma unroll
    for (int mi = 0; mi < 4; ++mi)
#pragma unroll
        for (int ni = 0; ni < 4; ++ni) { acc[mi][ni].x = 0.f; acc[mi][ni].y = 0.f; acc[mi][ni].z = 0.f; acc[mi][ni].w = 0.f; }
    const unsigned short* Ap = A + (size_t)m_base * KR;
    const unsigned short* Bp = BT + ((size_t)e * DEH + n_base) * KR;
    for (int k0 = 0; k0 < KR; k0 += 64) {
#pragma unroll
        for (int i = 0; i < 4; ++i) {
            const int ch = i * 256 + tid;
            const int r = ch >> 3, c = ch & 7;
            GLLDS16(Ap + (size_t)r * KR + k0 + c * 8, As + (i * 256 + wave * 64) * 8);
            GLLDS16(Bp + (size_t)r * KR + k0 + c * 8, Bs + (i * 256 + wave * 64) * 8);
        }
        __syncthreads();
#pragma unroll
        for (int kc = 0; kc < 2; ++kc) {
            bf16x8 af[4], bfr[4];
#pragma unroll
            for (int mi = 0; mi < 4; ++mi)
                af[mi] = *(const bf16x8*)(As + (wm + mi * 16 + l16) * 64 + kc * 32 + quad * 8);
#pragma unroll
            for (int ni = 0; ni < 4; ++ni)
                bfr[ni] = *(const bf16x8*)(Bs + (wn + ni * 16 + l16) * 64 + kc * 32 + quad * 8);
#pragma unroll
            for (int mi = 0; mi < 4; ++mi)
#pragma unroll
                for (int ni = 0; ni < 4; ++ni)
                    acc[mi][ni] = __builtin_amdgcn_mfma_f32_16x16x32_bf16(af[mi], bfr[ni], acc[mi][ni], 0, 0, 0);
        }
        __syncthreads();
    }
#pragma unroll
    for (int ni = 0; ni < 4; ++ni) {
        const int col = n_base + wn + ni * 16 + l16;
        const float bias = be1[e * DEH + col];
#pragma unroll
        for (int mi = 0; mi < 4; ++mi) {
            const int row = m_base + wm + mi * 16 + quad * 4;
#pragma unroll
            for (int r = 0; r < 4; ++r) {
                const float v = acc[mi][ni][r] + bias;
                const float gl = v / (1.0f + __expf(-1.5957691216057308f * (v + 0.044715f * v * v * v)));
                hh[(size_t)(row + r) * DEH + col] = f2bf(gl);
            }
        }
    }
}

// ---------- expert GEMM2: eo = hh @ We2[e] + be2[e] , bf16 MFMA ----------
__global__ __launch_bounds__(256) void gemm2(const unsigned short* __restrict__ A,
                                             const unsigned short* __restrict__ BT,
                                             const float* __restrict__ be2,
                                             unsigned short* __restrict__ eo,
                                             const int* __restrict__ offsets) {
    const int m_base = blockIdx.y * 128;
    if (m_base >= offsets[NE]) return;
    int e = 0;
    while (m_base >= offsets[e + 1]) ++e;
    const int n_base = blockIdx.x * 128;
    __shared__ unsigned short As[128 * 64];
    __shared__ unsigned short Bs[128 * 64];
    const int tid = threadIdx.x, lane = tid & 63, wave = tid >> 6;
    const int wm = (wave & 1) * 64, wn = (wave >> 1) * 64;
    const int l16 = lane & 15, quad = lane >> 4;
    f32x4 acc[4][4];
#pragma unroll
    for (int mi = 0; mi < 4; ++mi)
#pragma unroll
        for (int ni = 0; ni < 4; ++ni) { acc[mi][ni].x = 0.f; acc[mi][ni].y = 0.f; acc[mi][ni].z = 0.f; acc[mi][ni].w = 0.f; }
    const unsigned short* Ap = A + (size_t)m_base * DEH;
    const unsigned short* Bp = BT + ((size_t)e * DMODEL + n_base) * DEH;
    for (int k0 = 0; k0 < DEH; k0 += 64) {
#pragma unroll
        for (int i = 0; i < 4; ++i) {
            const int ch = i * 256 + tid;
            const int r = ch >> 3, c = ch & 7;
            GLLDS16(Ap + (size_t)r * DEH + k0 + c * 8, As + (i * 256 + wave * 64) * 8);
            GLLDS16(Bp + (size_t)r * DEH + k0 + c * 8, Bs + (i * 256 + wave * 64) * 8);
        }
        __syncthreads();
#pragma unroll
        for (int kc = 0; kc < 2; ++kc) {
            bf16x8 af[4], bfr[4];
#pragma unroll
            for (int mi = 0; mi < 4; ++mi)
                af[mi] = *(const bf16x8*)(As + (wm + mi * 16 + l16) * 64 + kc * 32 + quad * 8);
#pragma unroll
            for (int ni = 0; ni < 4; ++ni)
                bfr[ni] = *(const bf16x8*)(Bs + (wn + ni * 16 + l16) * 64 + kc * 32 + quad * 8);
#pragma unroll
            for (int mi = 0; mi < 4; ++mi)
#pragma unroll
                for (int ni = 0; ni < 4; ++ni)
                    acc[mi][ni] = __builtin_amdgcn_mfma_f32_16x16x32_bf16(af[mi], bfr[ni], acc[mi][ni], 0, 0, 0);
        }
        __syncthreads();
    }
#pragma unroll
    for (int ni = 0; ni < 4; ++ni) {
        const int col = n_base + wn + ni * 16 + l16;
        const float bias = be2[e * DMODEL + col];
#pragma unroll
        for (int mi = 0; mi < 4; ++mi) {
            const int row = m_base + wm + mi * 16 + quad * 4;
#pragma unroll
            for (int r = 0; r < 4; ++r)
                eo[(size_t)(row + r) * DMODEL + col] = f2bf(acc[mi][ni][r] + bias);
        }
    }
}

// ---------- combine: out = h + w0*eo[r0] + w1*eo[r1] ----------
__global__ __launch_bounds__(256) void kComb(const float* __restrict__ h, const unsigned short* __restrict__ eo,
                                             const int* __restrict__ tok2row, const float* __restrict__ top_w,
                                             float* __restrict__ out) {
    const int t = blockIdx.x, tid = threadIdx.x;
    const int r0 = tok2row[2 * t], r1 = tok2row[2 * t + 1];
    const float w0 = top_w[2 * t], w1 = top_w[2 * t + 1];
    const float4 hv = *(const float4*)(h + (size_t)t * DMODEL + tid * 4);
    const ushort4 a = *(const ushort4*)(eo + (size_t)r0 * DMODEL + tid * 4);
    const ushort4 b = *(const ushort4*)(eo + (size_t)r1 * DMODEL + tid * 4);
    float4 o;
    o.x = hv.x + w0 * bf2f(a.x) + w1 * bf2f(b.x);
    o.y = hv.y + w0 * bf2f(a.y) + w1 * bf2f(b.y);
    o.z = hv.z + w0 * bf2f(a.z) + w1 * bf2f(b.z);
    o.w = hv.w + w0 * bf2f(a.w) + w1 * bf2f(b.w);
    *(float4*)(out + (size_t)t * DMODEL + tid * 4) = o;
}

extern "C" void kernel_launch(void* const* d_in, const int* in_sizes, int n_in,
                              void* d_out, int out_size, void* d_ws, size_t ws_size,
                              hipStream_t stream) {
    const float* h    = (const float*)d_in[0];
    const float* feat = (const float*)d_in[1];
    const float* ln_g = (const float*)d_in[2];
    const float* ln_b = (const float*)d_in[3];
    const float* Wsf  = (const float*)d_in[4];
    const float* bsf  = (const float*)d_in[5];
    const float* Wr1  = (const float*)d_in[6];
    const float* br1  = (const float*)d_in[7];
    const float* Wr2  = (const float*)d_in[8];
    const float* br2  = (const float*)d_in[9];
    const float* Wef  = (const float*)d_in[10];
    const float* bef  = (const float*)d_in[11];
    const float* We1  = (const float*)d_in[12];
    const float* be1  = (const float*)d_in[13];
    const float* We2  = (const float*)d_in[14];
    const float* be2  = (const float*)d_in[15];
    const int* stage_idx  = (const int*)d_in[16];
    const int* expert_idx = (const int*)d_in[17];
    float* out = (float*)d_out;

    char* ws = (char*)d_ws;
    float*          rin  = (float*)(ws + 0);                       // 8192*1088*4  = 35651584
    unsigned short* hln  = (unsigned short*)(ws + 35651584);       // 8192*1024*2  = 16777216
    unsigned short* eemb = (unsigned short*)(ws + 52428800);       // 8192*8*64*2  = 8388608
    float*          hr   = (float*)(ws + 60817408);                // 8192*256*4   = 8388608
    unsigned short* hh   = (unsigned short*)(ws + 0);              // alias: 17408*2048*2 = 71303168
    unsigned short* xin  = (unsigned short*)(ws + 75497472);       // 17408*1088*2 = 37879808
    unsigned short* eo   = (unsigned short*)(ws + 75497472);       // alias: 17408*1024*2 = 35651584
    unsigned short* We1T = (unsigned short*)(ws + 113377280);      // 35651584
    unsigned short* We2T = (unsigned short*)(ws + 149028864);      // 33554432
    int*   top_e   = (int*)(ws + 182583296);
    float* top_w   = (float*)(ws + 182648832);
    int*   tok2row = (int*)(ws + 182714368);
    int*   rowtok  = (int*)(ws + 182779904);
    int*   counts  = (int*)(ws + 182849536);
    int*   fill    = (int*)(ws + 182849600);
    int*   offsets = (int*)(ws + 182849664);
    if (ws_size < 182849728) return;

    hipMemsetAsync(counts, 0, 128, stream);                  // counts + fill
    hipMemsetAsync(rowtok, 0xFF, MAXROWS * 4, stream);       // rowtok = -1

    kT<<<dim3(64, 34, 8), 256, 0, stream>>>(We1, We1T, KR, DEH);
    kT<<<dim3(32, 64, 8), 256, 0, stream>>>(We2, We2T, DEH, DMODEL);
    kA<<<T_TOK, 256, 0, stream>>>(h, feat, ln_g, ln_b, Wsf, bsf, Wef, bef,
                                  stage_idx, expert_idx, rin, hln, eemb);
    kB<<<dim3(DRH / 64, T_TOK / 64), 256, 0, stream>>>(rin, Wr1, br1, hr);
    kC<<<T_TOK / 4, 256, 0, stream>>>(hr, Wr2, br2, top_e, top_w);
    kCnt<<<T_TOK / 256, 256, 0, stream>>>(top_e, counts);
    kD<<<1, 64, 0, stream>>>(counts, offsets);
    kE<<<T_TOK / 256, 256, 0, stream>>>(top_e, offsets, fill, rowtok, tok2row);
    kF<<<MAXROWS, 128, 0, stream>>>(hln, eemb, rowtok, offsets, xin);
    gemm1<<<dim3(DEH / 128, MAXMT), 256, 0, stream>>>(xin, We1T, be1, hh, offsets);
    gemm2<<<dim3(DMODEL / 128, MAXMT), 256, 0, stream>>>(hh, We2T, be2, eo, offsets);
    kComb<<<T_TOK, 256, 0, stream>>>(h, eo, tok2row, top_w, out);
}

// Round 3
// 625.260 us; speedup vs baseline: 1.4319x; 1.0184x over previous
//
#include <hip/hip_runtime.h>

// ---------- constants ----------
#define T_TOK   8192
#define DMODEL  1024
#define KR      1088      // D + DFE
#define DFE     64
#define DRH     256
#define NE      8
#define DEH     2048
#define MAXROWS 17408
#define MAXMT   136

typedef __bf16 bf16x8 __attribute__((ext_vector_type(8)));
typedef float  f32x4  __attribute__((ext_vector_type(4)));

__device__ __forceinline__ unsigned short f2bf(float f) {
    union { float f; unsigned u; } v; v.f = f;
    unsigned u = v.u;
    u += 0x7FFFu + ((u >> 16) & 1u);   // RNE
    return (unsigned short)(u >> 16);
}
__device__ __forceinline__ float bf2f(unsigned short s) {
    union { unsigned u; float f; } v; v.u = ((unsigned)s) << 16;
    return v.f;
}

#define GLLDS16(gp, lp) \
    __builtin_amdgcn_global_load_lds((const __attribute__((address_space(1))) void*)(gp), \
                                     (__attribute__((address_space(3))) void*)(lp), 16, 0, 0)

// ---------- kernel W: fp32 [E][R][C] -> bf16 [E][C][R] (transpose+convert) ----------
__global__ __launch_bounds__(256) void kT(const float* __restrict__ in,
                                          unsigned short* __restrict__ outT,
                                          int R, int C) {
    __shared__ float tile[32][33];
    const int e = blockIdx.z;
    const float* src = in + (size_t)e * R * C;
    unsigned short* dst = outT + (size_t)e * R * C;
    const int tx = threadIdx.x & 31, ty = threadIdx.x >> 5;
    const int r0 = blockIdx.y * 32, c0 = blockIdx.x * 32;
#pragma unroll
    for (int p = 0; p < 4; ++p)
        tile[ty + p * 8][tx] = src[(size_t)(r0 + ty + p * 8) * C + c0 + tx];
    __syncthreads();
#pragma unroll
    for (int p = 0; p < 4; ++p)
        dst[(size_t)(c0 + ty + p * 8) * R + r0 + tx] = f2bf(tile[tx][ty + p * 8]);
}

// ---------- kernel A: layernorm + stage-feature emb + expert-feature emb ----------
__global__ __launch_bounds__(256) void kA(const float* __restrict__ h, const float* __restrict__ feat,
                                          const float* __restrict__ ln_g, const float* __restrict__ ln_b,
                                          const float* __restrict__ Wsf, const float* __restrict__ bsf,
                                          const float* __restrict__ Wef, const float* __restrict__ bef,
                                          const int* __restrict__ stage_idx, const int* __restrict__ expert_idx,
                                          float* __restrict__ rin, unsigned short* __restrict__ hln,
                                          unsigned short* __restrict__ eemb) {
    const int t = blockIdx.x, tid = threadIdx.x;
    __shared__ float featrow[32];
    __shared__ float red[8];
    if (tid < 32) featrow[tid] = feat[t * 32 + tid];
    const float4 x = *(const float4*)(h + (size_t)t * DMODEL + tid * 4);
    float s = x.x + x.y + x.z + x.w;
#pragma unroll
    for (int off = 32; off > 0; off >>= 1) s += __shfl_xor(s, off);
    if ((tid & 63) == 0) red[tid >> 6] = s;
    __syncthreads();
    const float mean = (red[0] + red[1] + red[2] + red[3]) * (1.0f / 1024.0f);
    const float dx = x.x - mean, dy = x.y - mean, dz = x.z - mean, dw = x.w - mean;
    float q = dx * dx + dy * dy + dz * dz + dw * dw;
#pragma unroll
    for (int off = 32; off > 0; off >>= 1) q += __shfl_xor(q, off);
    if ((tid & 63) == 0) red[4 + (tid >> 6)] = q;
    __syncthreads();
    const float var = (red[4] + red[5] + red[6] + red[7]) * (1.0f / 1024.0f);
    const float inv = 1.0f / sqrtf(var + 1e-5f);
    const float4 g = *(const float4*)(ln_g + tid * 4);
    const float4 b = *(const float4*)(ln_b + tid * 4);
    float4 y;
    y.x = dx * inv * g.x + b.x; y.y = dy * inv * g.y + b.y;
    y.z = dz * inv * g.z + b.z; y.w = dw * inv * g.w + b.w;
    *(float4*)(rin + (size_t)t * KR + tid * 4) = y;
    ushort4 yb; yb.x = f2bf(y.x); yb.y = f2bf(y.y); yb.z = f2bf(y.z); yb.w = f2bf(y.w);
    *(ushort4*)(hln + (size_t)t * DMODEL + tid * 4) = yb;
    if (tid < 64) {  // stage-feature embedding (router input tail), fp32
        float a = bsf[tid];
#pragma unroll
        for (int f = 0; f < 16; ++f) a += featrow[stage_idx[f]] * Wsf[f * DFE + tid];
        rin[(size_t)t * KR + DMODEL + tid] = a;
    }
#pragma unroll
    for (int it = 0; it < 2; ++it) {  // expert-feature embeddings, bf16
        const int idx = it * 256 + tid;
        const int e = idx >> 6, d = idx & 63;
        float a = bef[e * DFE + d];
#pragma unroll
        for (int f = 0; f < 8; ++f) a += featrow[expert_idx[e * 8 + f]] * Wef[(e * 8 + f) * DFE + d];
        eemb[((size_t)t * NE + e) * DFE + d] = f2bf(a);
    }
}

// ---------- kernel B: router GEMM1 fp32 + gelu(tanh) : hr = gelu(rin @ Wr1 + br1) ----------
__global__ __launch_bounds__(256) void kB(const float* __restrict__ rin, const float* __restrict__ Wr1,
                                          const float* __restrict__ br1, float* __restrict__ hr) {
    __shared__ float As[16][72];   // [k][m], padded
    __shared__ float Bs[16][64];   // [k][n]
    const int tid = threadIdx.x;
    const int m0 = blockIdx.y * 64, n0 = blockIdx.x * 64;
    const int tm = tid & 15, tn = tid >> 4;
    const int ar = tid >> 2, ak = (tid & 3) * 4;
    const int bk = tid >> 4, bn = (tid & 15) * 4;
    float acc[4][4] = {};
    for (int k0 = 0; k0 < KR; k0 += 16) {
        const float4 av = *(const float4*)(rin + (size_t)(m0 + ar) * KR + k0 + ak);
        const float4 bv = *(const float4*)(Wr1 + (size_t)(k0 + bk) * DRH + n0 + bn);
        __syncthreads();
        As[ak + 0][ar] = av.x; As[ak + 1][ar] = av.y; As[ak + 2][ar] = av.z; As[ak + 3][ar] = av.w;
        *(float4*)&Bs[bk][bn] = bv;
        __syncthreads();
#pragma unroll
        for (int kk = 0; kk < 16; ++kk) {
            const float4 a = *(const float4*)&As[kk][tm * 4];
            const float4 bq = *(const float4*)&Bs[kk][tn * 4];
            acc[0][0] += a.x * bq.x; acc[0][1] += a.x * bq.y; acc[0][2] += a.x * bq.z; acc[0][3] += a.x * bq.w;
            acc[1][0] += a.y * bq.x; acc[1][1] += a.y * bq.y; acc[1][2] += a.y * bq.z; acc[1][3] += a.y * bq.w;
            acc[2][0] += a.z * bq.x; acc[2][1] += a.z * bq.y; acc[2][2] += a.z * bq.z; acc[2][3] += a.z * bq.w;
            acc[3][0] += a.w * bq.x; acc[3][1] += a.w * bq.y; acc[3][2] += a.w * bq.z; acc[3][3] += a.w * bq.w;
        }
    }
#pragma unroll
    for (int i = 0; i < 4; ++i) {
        const int row = m0 + tm * 4 + i;
#pragma unroll
        for (int j = 0; j < 4; ++j) {
            const int col = n0 + tn * 4 + j;
            const float v = acc[i][j] + br1[col];
            const float u = 0.7978845608028654f * (v + 0.044715f * v * v * v);
            hr[(size_t)row * DRH + col] = 0.5f * v * (1.0f + tanhf(u));
        }
    }
}

// ---------- kernel C: router head + top-2 softmax gating (NO atomics) ----------
__global__ __launch_bounds__(256) void kC(const float* __restrict__ hr, const float* __restrict__ Wr2,
                                          const float* __restrict__ br2, int* __restrict__ top_e,
                                          float* __restrict__ top_w) {
    const int tid = threadIdx.x, lane = tid & 63, w = tid >> 6;
    const int t = blockIdx.x * 4 + w;
    float acc[8] = {};
#pragma unroll
    for (int r = 0; r < 4; ++r) {
        const int k = r * 64 + lane;
        const float hv = hr[(size_t)t * DRH + k];
        const float4 w0 = *(const float4*)(Wr2 + k * 8);
        const float4 w1 = *(const float4*)(Wr2 + k * 8 + 4);
        acc[0] += hv * w0.x; acc[1] += hv * w0.y; acc[2] += hv * w0.z; acc[3] += hv * w0.w;
        acc[4] += hv * w1.x; acc[5] += hv * w1.y; acc[6] += hv * w1.z; acc[7] += hv * w1.w;
    }
#pragma unroll
    for (int off = 32; off > 0; off >>= 1)
#pragma unroll
        for (int j = 0; j < 8; ++j) acc[j] += __shfl_xor(acc[j], off);
    if (lane == 0) {
#pragma unroll
        for (int j = 0; j < 8; ++j) acc[j] += br2[j];
        float v1 = -1e30f; int i1 = 0;
#pragma unroll
        for (int j = 0; j < 8; ++j) if (acc[j] > v1) { v1 = acc[j]; i1 = j; }
        float v2 = -1e30f; int i2 = 0;
#pragma unroll
        for (int j = 0; j < 8; ++j) if (j != i1 && acc[j] > v2) { v2 = acc[j]; i2 = j; }
        const float e2 = expf(v2 - v1);
        const float inv = 1.0f / (1.0f + e2);
        top_e[2 * t] = i1; top_e[2 * t + 1] = i2;
        top_w[2 * t] = inv; top_w[2 * t + 1] = e2 * inv;
    }
}

// ---------- kernel Cnt: LDS-privatized expert histogram ----------
__global__ __launch_bounds__(256) void kCnt(const int* __restrict__ top_e, int* __restrict__ counts) {
    __shared__ int lc[NE];
    const int tid = threadIdx.x;
    if (tid < NE) lc[tid] = 0;
    __syncthreads();
    const int t = blockIdx.x * 256 + tid;
    atomicAdd(&lc[top_e[2 * t]], 1);
    atomicAdd(&lc[top_e[2 * t + 1]], 1);
    __syncthreads();
    if (tid < NE) atomicAdd(&counts[tid], lc[tid]);
}

// ---------- kernel D: padded prefix sum over expert counts ----------
__global__ void kD(const int* __restrict__ counts, int* __restrict__ offsets) {
    if (threadIdx.x == 0) {
        int off = 0;
        for (int e = 0; e < NE; ++e) { offsets[e] = off; off += (counts[e] + 127) & ~127; }
        offsets[NE] = off;
    }
}

// ---------- kernel E: scatter token->row, block-aggregated ----------
__global__ __launch_bounds__(256) void kE(const int* __restrict__ top_e, const int* __restrict__ offsets,
                                          int* __restrict__ fill, int* __restrict__ rowtok,
                                          int* __restrict__ tok2row) {
    __shared__ int lc[NE], lbase[NE], lpos[NE];
    const int tid = threadIdx.x;
    if (tid < NE) { lc[tid] = 0; lpos[tid] = 0; }
    __syncthreads();
    const int t = blockIdx.x * 256 + tid;
    const int e0 = top_e[2 * t], e1 = top_e[2 * t + 1];
    atomicAdd(&lc[e0], 1);
    atomicAdd(&lc[e1], 1);
    __syncthreads();
    if (tid < NE) lbase[tid] = atomicAdd(&fill[tid], lc[tid]);
    __syncthreads();
    const int p0 = atomicAdd(&lpos[e0], 1);
    const int p1 = atomicAdd(&lpos[e1], 1);
    const int r0 = offsets[e0] + lbase[e0] + p0;
    const int r1 = offsets[e1] + lbase[e1] + p1;
    rowtok[r0] = t; rowtok[r1] = t;
    tok2row[2 * t] = r0; tok2row[2 * t + 1] = r1;
}

// ---------- kernel F: gather per-assignment A rows [hln | eemb(e)] ----------
__global__ __launch_bounds__(128) void kF(const unsigned short* __restrict__ hln,
                                          const unsigned short* __restrict__ eemb,
                                          const int* __restrict__ rowtok, const int* __restrict__ offsets,
                                          unsigned short* __restrict__ xin) {
    const int row = blockIdx.x;
    if (row >= offsets[NE]) return;
    const int tid = threadIdx.x;
    const int t = rowtok[row];
    uint4* dst = (uint4*)(xin + (size_t)row * KR);
    if (t < 0) {
        const uint4 z = {0u, 0u, 0u, 0u};
        dst[tid] = z;
        if (tid < 8) dst[128 + tid] = z;
    } else {
        int e = 0;
        while (row >= offsets[e + 1]) ++e;
        dst[tid] = ((const uint4*)(hln + (size_t)t * DMODEL))[tid];
        if (tid < 8) dst[128 + tid] = ((const uint4*)(eemb + ((size_t)t * NE + e) * DFE))[tid];
    }
}

// ---------- expert GEMM1: hh = gelu(xin @ We1[e] + be1[e]) , bf16 MFMA ----------
// LDS chunk index XOR-swizzled by (row&7): kills the 16-way bank conflict of the
// row-major [128][64] layout (row stride = 128 B = full bank rotation).
__global__ __launch_bounds__(256) void gemm1(const unsigned short* __restrict__ A,
                                             const unsigned short* __restrict__ BT,
                                             const float* __restrict__ be1,
                                             unsigned short* __restrict__ hh,
                                             const int* __restrict__ offsets) {
    const int m_base = blockIdx.y * 128;
    if (m_base >= offsets[NE]) return;
    int e = 0;
    while (m_base >= offsets[e + 1]) ++e;
    const int n_base = blockIdx.x * 128;
    __shared__ unsigned short As[128 * 64];
    __shared__ unsigned short Bs[128 * 64];
    const int tid = threadIdx.x, lane = tid & 63, wave = tid >> 6;
    const int wm = (wave & 1) * 64, wn = (wave >> 1) * 64;
    const int l16 = lane & 15, quad = lane >> 4;
    const int sw = l16 & 7;                 // read-side swizzle key (row&7 == l16&7)
    f32x4 acc[4][4];
#pragma unroll
    for (int mi = 0; mi < 4; ++mi)
#pragma unroll
        for (int ni = 0; ni < 4; ++ni) { acc[mi][ni].x = 0.f; acc[mi][ni].y = 0.f; acc[mi][ni].z = 0.f; acc[mi][ni].w = 0.f; }
    const unsigned short* Ap = A + (size_t)m_base * KR;
    const unsigned short* Bp = BT + ((size_t)e * DEH + n_base) * KR;
    for (int k0 = 0; k0 < KR; k0 += 64) {
#pragma unroll
        for (int i = 0; i < 4; ++i) {
            const int ch = i * 256 + tid;
            const int r = ch >> 3, c = (ch & 7) ^ (r & 7);   // store-side swizzle
            GLLDS16(Ap + (size_t)r * KR + k0 + c * 8, As + (i * 256 + wave * 64) * 8);
            GLLDS16(Bp + (size_t)r * KR + k0 + c * 8, Bs + (i * 256 + wave * 64) * 8);
        }
        __syncthreads();
#pragma unroll
        for (int kc = 0; kc < 2; ++kc) {
            bf16x8 af[4], bfr[4];
#pragma unroll
            for (int mi = 0; mi < 4; ++mi)
                af[mi] = *(const bf16x8*)(As + (wm + mi * 16 + l16) * 64 + (((kc * 4 + quad) ^ sw) * 8));
#pragma unroll
            for (int ni = 0; ni < 4; ++ni)
                bfr[ni] = *(const bf16x8*)(Bs + (wn + ni * 16 + l16) * 64 + (((kc * 4 + quad) ^ sw) * 8));
#pragma unroll
            for (int mi = 0; mi < 4; ++mi)
#pragma unroll
                for (int ni = 0; ni < 4; ++ni)
                    acc[mi][ni] = __builtin_amdgcn_mfma_f32_16x16x32_bf16(af[mi], bfr[ni], acc[mi][ni], 0, 0, 0);
        }
        __syncthreads();
    }
#pragma unroll
    for (int ni = 0; ni < 4; ++ni) {
        const int col = n_base + wn + ni * 16 + l16;
        const float bias = be1[e * DEH + col];
#pragma unroll
        for (int mi = 0; mi < 4; ++mi) {
            const int row = m_base + wm + mi * 16 + quad * 4;
#pragma unroll
            for (int r = 0; r < 4; ++r) {
                const float v = acc[mi][ni][r] + bias;
                const float gl = v / (1.0f + __expf(-1.5957691216057308f * (v + 0.044715f * v * v * v)));
                hh[(size_t)(row + r) * DEH + col] = f2bf(gl);
            }
        }
    }
}

// ---------- expert GEMM2: eo = hh @ We2[e] + be2[e] , bf16 MFMA (same swizzle) ----------
__global__ __launch_bounds__(256) void gemm2(const unsigned short* __restrict__ A,
                                             const unsigned short* __restrict__ BT,
                                             const float* __restrict__ be2,
                                             unsigned short* __restrict__ eo,
                                             const int* __restrict__ offsets) {
    const int m_base = blockIdx.y * 128;
    if (m_base >= offsets[NE]) return;
    int e = 0;
    while (m_base >= offsets[e + 1]) ++e;
    const int n_base = blockIdx.x * 128;
    __shared__ unsigned short As[128 * 64];
    __shared__ unsigned short Bs[128 * 64];
    const int tid = threadIdx.x, lane = tid & 63, wave = tid >> 6;
    const int wm = (wave & 1) * 64, wn = (wave >> 1) * 64;
    const int l16 = lane & 15, quad = lane >> 4;
    const int sw = l16 & 7;
    f32x4 acc[4][4];
#pragma unroll
    for (int mi = 0; mi < 4; ++mi)
#pragma unroll
        for (int ni = 0; ni < 4; ++ni) { acc[mi][ni].x = 0.f; acc[mi][ni].y = 0.f; acc[mi][ni].z = 0.f; acc[mi][ni].w = 0.f; }
    const unsigned short* Ap = A + (size_t)m_base * DEH;
    const unsigned short* Bp = BT + ((size_t)e * DMODEL + n_base) * DEH;
    for (int k0 = 0; k0 < DEH; k0 += 64) {
#pragma unroll
        for (int i = 0; i < 4; ++i) {
            const int ch = i * 256 + tid;
            const int r = ch >> 3, c = (ch & 7) ^ (r & 7);
            GLLDS16(Ap + (size_t)r * DEH + k0 + c * 8, As + (i * 256 + wave * 64) * 8);
            GLLDS16(Bp + (size_t)r * DEH + k0 + c * 8, Bs + (i * 256 + wave * 64) * 8);
        }
        __syncthreads();
#pragma unroll
        for (int kc = 0; kc < 2; ++kc) {
            bf16x8 af[4], bfr[4];
#pragma unroll
            for (int mi = 0; mi < 4; ++mi)
                af[mi] = *(const bf16x8*)(As + (wm + mi * 16 + l16) * 64 + (((kc * 4 + quad) ^ sw) * 8));
#pragma unroll
            for (int ni = 0; ni < 4; ++ni)
                bfr[ni] = *(const bf16x8*)(Bs + (wn + ni * 16 + l16) * 64 + (((kc * 4 + quad) ^ sw) * 8));
#pragma unroll
            for (int mi = 0; mi < 4; ++mi)
#pragma unroll
                for (int ni = 0; ni < 4; ++ni)
                    acc[mi][ni] = __builtin_amdgcn_mfma_f32_16x16x32_bf16(af[mi], bfr[ni], acc[mi][ni], 0, 0, 0);
        }
        __syncthreads();
    }
#pragma unroll
    for (int ni = 0; ni < 4; ++ni) {
        const int col = n_base + wn + ni * 16 + l16;
        const float bias = be2[e * DMODEL + col];
#pragma unroll
        for (int mi = 0; mi < 4; ++mi) {
            const int row = m_base + wm + mi * 16 + quad * 4;
#pragma unroll
            for (int r = 0; r < 4; ++r)
                eo[(size_t)(row + r) * DMODEL + col] = f2bf(acc[mi][ni][r] + bias);
        }
    }
}

// ---------- combine: out = h + w0*eo[r0] + w1*eo[r1] ----------
__global__ __launch_bounds__(256) void kComb(const float* __restrict__ h, const unsigned short* __restrict__ eo,
                                             const int* __restrict__ tok2row, const float* __restrict__ top_w,
                                             float* __restrict__ out) {
    const int t = blockIdx.x, tid = threadIdx.x;
    const int r0 = tok2row[2 * t], r1 = tok2row[2 * t + 1];
    const float w0 = top_w[2 * t], w1 = top_w[2 * t + 1];
    const float4 hv = *(const float4*)(h + (size_t)t * DMODEL + tid * 4);
    const ushort4 a = *(const ushort4*)(eo + (size_t)r0 * DMODEL + tid * 4);
    const ushort4 b = *(const ushort4*)(eo + (size_t)r1 * DMODEL + tid * 4);
    float4 o;
    o.x = hv.x + w0 * bf2f(a.x) + w1 * bf2f(b.x);
    o.y = hv.y + w0 * bf2f(a.y) + w1 * bf2f(b.y);
    o.z = hv.z + w0 * bf2f(a.z) + w1 * bf2f(b.z);
    o.w = hv.w + w0 * bf2f(a.w) + w1 * bf2f(b.w);
    *(float4*)(out + (size_t)t * DMODEL + tid * 4) = o;
}

extern "C" void kernel_launch(void* const* d_in, const int* in_sizes, int n_in,
                              void* d_out, int out_size, void* d_ws, size_t ws_size,
                              hipStream_t stream) {
    const float* h    = (const float*)d_in[0];
    const float* feat = (const float*)d_in[1];
    const float* ln_g = (const float*)d_in[2];
    const float* ln_b = (const float*)d_in[3];
    const float* Wsf  = (const float*)d_in[4];
    const float* bsf  = (const float*)d_in[5];
    const float* Wr1  = (const float*)d_in[6];
    const float* br1  = (const float*)d_in[7];
    const float* Wr2  = (const float*)d_in[8];
    const float* br2  = (const float*)d_in[9];
    const float* Wef  = (const float*)d_in[10];
    const float* bef  = (const float*)d_in[11];
    const float* We1  = (const float*)d_in[12];
    const float* be1  = (const float*)d_in[13];
    const float* We2  = (const float*)d_in[14];
    const float* be2  = (const float*)d_in[15];
    const int* stage_idx  = (const int*)d_in[16];
    const int* expert_idx = (const int*)d_in[17];
    float* out = (float*)d_out;

    char* ws = (char*)d_ws;
    float*          rin  = (float*)(ws + 0);                       // 8192*1088*4  = 35651584
    unsigned short* hln  = (unsigned short*)(ws + 35651584);       // 8192*1024*2  = 16777216
    unsigned short* eemb = (unsigned short*)(ws + 52428800);       // 8192*8*64*2  = 8388608
    float*          hr   = (float*)(ws + 60817408);                // 8192*256*4   = 8388608
    unsigned short* hh   = (unsigned short*)(ws + 0);              // alias: 17408*2048*2 = 71303168
    unsigned short* xin  = (unsigned short*)(ws + 75497472);       // 17408*1088*2 = 37879808
    unsigned short* eo   = (unsigned short*)(ws + 75497472);       // alias: 17408*1024*2 = 35651584
    unsigned short* We1T = (unsigned short*)(ws + 113377280);      // 35651584
    unsigned short* We2T = (unsigned short*)(ws + 149028864);      // 33554432
    int*   top_e   = (int*)(ws + 182583296);
    float* top_w   = (float*)(ws + 182648832);
    int*   tok2row = (int*)(ws + 182714368);
    int*   rowtok  = (int*)(ws + 182779904);
    int*   counts  = (int*)(ws + 182849536);
    int*   fill    = (int*)(ws + 182849600);
    int*   offsets = (int*)(ws + 182849664);
    if (ws_size < 182849728) return;

    hipMemsetAsync(counts, 0, 128, stream);                  // counts + fill
    hipMemsetAsync(rowtok, 0xFF, MAXROWS * 4, stream);       // rowtok = -1

    kT<<<dim3(64, 34, 8), 256, 0, stream>>>(We1, We1T, KR, DEH);
    kT<<<dim3(32, 64, 8), 256, 0, stream>>>(We2, We2T, DEH, DMODEL);
    kA<<<T_TOK, 256, 0, stream>>>(h, feat, ln_g, ln_b, Wsf, bsf, Wef, bef,
                                  stage_idx, expert_idx, rin, hln, eemb);
    kB<<<dim3(DRH / 64, T_TOK / 64), 256, 0, stream>>>(rin, Wr1, br1, hr);
    kC<<<T_TOK / 4, 256, 0, stream>>>(hr, Wr2, br2, top_e, top_w);
    kCnt<<<T_TOK / 256, 256, 0, stream>>>(top_e, counts);
    kD<<<1, 64, 0, stream>>>(counts, offsets);
    kE<<<T_TOK / 256, 256, 0, stream>>>(top_e, offsets, fill, rowtok, tok2row);
    kF<<<MAXROWS, 128, 0, stream>>>(hln, eemb, rowtok, offsets, xin);
    gemm1<<<dim3(DEH / 128, MAXMT), 256, 0, stream>>>(xin, We1T, be1, hh, offsets);
    gemm2<<<dim3(DMODEL / 128, MAXMT), 256, 0, stream>>>(hh, We2T, be2, eo, offsets);
    kComb<<<T_TOK, 256, 0, stream>>>(h, eo, tok2row, top_w, out);
}

// Round 4
// 573.051 us; speedup vs baseline: 1.5623x; 1.0911x over previous
//
#include <hip/hip_runtime.h>

// ---------- constants ----------
#define T_TOK   8192
#define DMODEL  1024
#define KR      1088      // D + DFE
#define DFE     64
#define DRH     256
#define NE      8
#define DEH     2048
#define MAXROWS 17408
#define MAXMT   136

typedef __bf16 bf16x8 __attribute__((ext_vector_type(8)));
typedef float  f32x4  __attribute__((ext_vector_type(4)));

__device__ __forceinline__ unsigned short f2bf(float f) {
    union { float f; unsigned u; } v; v.f = f;
    unsigned u = v.u;
    u += 0x7FFFu + ((u >> 16) & 1u);   // RNE
    return (unsigned short)(u >> 16);
}
__device__ __forceinline__ float bf2f(unsigned short s) {
    union { unsigned u; float f; } v; v.u = ((unsigned)s) << 16;
    return v.f;
}

#define GLLDS16(gp, lp) \
    __builtin_amdgcn_global_load_lds((const __attribute__((address_space(1))) void*)(gp), \
                                     (__attribute__((address_space(3))) void*)(lp), 16, 0, 0)

// ---------- kernel W: fp32 [E][R][C] -> bf16 [E][C][R] (transpose+convert) ----------
__global__ __launch_bounds__(256) void kT(const float* __restrict__ in,
                                          unsigned short* __restrict__ outT,
                                          int R, int C) {
    __shared__ float tile[32][33];
    const int e = blockIdx.z;
    const float* src = in + (size_t)e * R * C;
    unsigned short* dst = outT + (size_t)e * R * C;
    const int tx = threadIdx.x & 31, ty = threadIdx.x >> 5;
    const int r0 = blockIdx.y * 32, c0 = blockIdx.x * 32;
#pragma unroll
    for (int p = 0; p < 4; ++p)
        tile[ty + p * 8][tx] = src[(size_t)(r0 + ty + p * 8) * C + c0 + tx];
    __syncthreads();
#pragma unroll
    for (int p = 0; p < 4; ++p)
        dst[(size_t)(c0 + ty + p * 8) * R + r0 + tx] = f2bf(tile[tx][ty + p * 8]);
}

// ---------- kernel A: layernorm + stage-feature emb + expert-feature emb ----------
__global__ __launch_bounds__(256) void kA(const float* __restrict__ h, const float* __restrict__ feat,
                                          const float* __restrict__ ln_g, const float* __restrict__ ln_b,
                                          const float* __restrict__ Wsf, const float* __restrict__ bsf,
                                          const float* __restrict__ Wef, const float* __restrict__ bef,
                                          const int* __restrict__ stage_idx, const int* __restrict__ expert_idx,
                                          float* __restrict__ rin, unsigned short* __restrict__ hln,
                                          unsigned short* __restrict__ eemb) {
    const int t = blockIdx.x, tid = threadIdx.x;
    __shared__ float featrow[32];
    __shared__ float red[8];
    if (tid < 32) featrow[tid] = feat[t * 32 + tid];
    const float4 x = *(const float4*)(h + (size_t)t * DMODEL + tid * 4);
    float s = x.x + x.y + x.z + x.w;
#pragma unroll
    for (int off = 32; off > 0; off >>= 1) s += __shfl_xor(s, off);
    if ((tid & 63) == 0) red[tid >> 6] = s;
    __syncthreads();
    const float mean = (red[0] + red[1] + red[2] + red[3]) * (1.0f / 1024.0f);
    const float dx = x.x - mean, dy = x.y - mean, dz = x.z - mean, dw = x.w - mean;
    float q = dx * dx + dy * dy + dz * dz + dw * dw;
#pragma unroll
    for (int off = 32; off > 0; off >>= 1) q += __shfl_xor(q, off);
    if ((tid & 63) == 0) red[4 + (tid >> 6)] = q;
    __syncthreads();
    const float var = (red[4] + red[5] + red[6] + red[7]) * (1.0f / 1024.0f);
    const float inv = 1.0f / sqrtf(var + 1e-5f);
    const float4 g = *(const float4*)(ln_g + tid * 4);
    const float4 b = *(const float4*)(ln_b + tid * 4);
    float4 y;
    y.x = dx * inv * g.x + b.x; y.y = dy * inv * g.y + b.y;
    y.z = dz * inv * g.z + b.z; y.w = dw * inv * g.w + b.w;
    *(float4*)(rin + (size_t)t * KR + tid * 4) = y;
    ushort4 yb; yb.x = f2bf(y.x); yb.y = f2bf(y.y); yb.z = f2bf(y.z); yb.w = f2bf(y.w);
    *(ushort4*)(hln + (size_t)t * DMODEL + tid * 4) = yb;
    if (tid < 64) {  // stage-feature embedding (router input tail), fp32
        float a = bsf[tid];
#pragma unroll
        for (int f = 0; f < 16; ++f) a += featrow[stage_idx[f]] * Wsf[f * DFE + tid];
        rin[(size_t)t * KR + DMODEL + tid] = a;
    }
#pragma unroll
    for (int it = 0; it < 2; ++it) {  // expert-feature embeddings, bf16
        const int idx = it * 256 + tid;
        const int e = idx >> 6, d = idx & 63;
        float a = bef[e * DFE + d];
#pragma unroll
        for (int f = 0; f < 8; ++f) a += featrow[expert_idx[e * 8 + f]] * Wef[(e * 8 + f) * DFE + d];
        eemb[((size_t)t * NE + e) * DFE + d] = f2bf(a);
    }
}

// ---------- kernel B: router GEMM1 fp32 + gelu(tanh) : hr = gelu(rin @ Wr1 + br1) ----------
__global__ __launch_bounds__(256) void kB(const float* __restrict__ rin, const float* __restrict__ Wr1,
                                          const float* __restrict__ br1, float* __restrict__ hr) {
    __shared__ float As[16][72];   // [k][m], padded
    __shared__ float Bs[16][64];   // [k][n]
    const int tid = threadIdx.x;
    const int m0 = blockIdx.y * 64, n0 = blockIdx.x * 64;
    const int tm = tid & 15, tn = tid >> 4;
    const int ar = tid >> 2, ak = (tid & 3) * 4;
    const int bk = tid >> 4, bn = (tid & 15) * 4;
    float acc[4][4] = {};
    for (int k0 = 0; k0 < KR; k0 += 16) {
        const float4 av = *(const float4*)(rin + (size_t)(m0 + ar) * KR + k0 + ak);
        const float4 bv = *(const float4*)(Wr1 + (size_t)(k0 + bk) * DRH + n0 + bn);
        __syncthreads();
        As[ak + 0][ar] = av.x; As[ak + 1][ar] = av.y; As[ak + 2][ar] = av.z; As[ak + 3][ar] = av.w;
        *(float4*)&Bs[bk][bn] = bv;
        __syncthreads();
#pragma unroll
        for (int kk = 0; kk < 16; ++kk) {
            const float4 a = *(const float4*)&As[kk][tm * 4];
            const float4 bq = *(const float4*)&Bs[kk][tn * 4];
            acc[0][0] += a.x * bq.x; acc[0][1] += a.x * bq.y; acc[0][2] += a.x * bq.z; acc[0][3] += a.x * bq.w;
            acc[1][0] += a.y * bq.x; acc[1][1] += a.y * bq.y; acc[1][2] += a.y * bq.z; acc[1][3] += a.y * bq.w;
            acc[2][0] += a.z * bq.x; acc[2][1] += a.z * bq.y; acc[2][2] += a.z * bq.z; acc[2][3] += a.z * bq.w;
            acc[3][0] += a.w * bq.x; acc[3][1] += a.w * bq.y; acc[3][2] += a.w * bq.z; acc[3][3] += a.w * bq.w;
        }
    }
#pragma unroll
    for (int i = 0; i < 4; ++i) {
        const int row = m0 + tm * 4 + i;
#pragma unroll
        for (int j = 0; j < 4; ++j) {
            const int col = n0 + tn * 4 + j;
            const float v = acc[i][j] + br1[col];
            const float u = 0.7978845608028654f * (v + 0.044715f * v * v * v);
            hr[(size_t)row * DRH + col] = 0.5f * v * (1.0f + tanhf(u));
        }
    }
}

// ---------- kernel C: router head + top-2 softmax gating (NO atomics) ----------
__global__ __launch_bounds__(256) void kC(const float* __restrict__ hr, const float* __restrict__ Wr2,
                                          const float* __restrict__ br2, int* __restrict__ top_e,
                                          float* __restrict__ top_w) {
    const int tid = threadIdx.x, lane = tid & 63, w = tid >> 6;
    const int t = blockIdx.x * 4 + w;
    float acc[8] = {};
#pragma unroll
    for (int r = 0; r < 4; ++r) {
        const int k = r * 64 + lane;
        const float hv = hr[(size_t)t * DRH + k];
        const float4 w0 = *(const float4*)(Wr2 + k * 8);
        const float4 w1 = *(const float4*)(Wr2 + k * 8 + 4);
        acc[0] += hv * w0.x; acc[1] += hv * w0.y; acc[2] += hv * w0.z; acc[3] += hv * w0.w;
        acc[4] += hv * w1.x; acc[5] += hv * w1.y; acc[6] += hv * w1.z; acc[7] += hv * w1.w;
    }
#pragma unroll
    for (int off = 32; off > 0; off >>= 1)
#pragma unroll
        for (int j = 0; j < 8; ++j) acc[j] += __shfl_xor(acc[j], off);
    if (lane == 0) {
#pragma unroll
        for (int j = 0; j < 8; ++j) acc[j] += br2[j];
        float v1 = -1e30f; int i1 = 0;
#pragma unroll
        for (int j = 0; j < 8; ++j) if (acc[j] > v1) { v1 = acc[j]; i1 = j; }
        float v2 = -1e30f; int i2 = 0;
#pragma unroll
        for (int j = 0; j < 8; ++j) if (j != i1 && acc[j] > v2) { v2 = acc[j]; i2 = j; }
        const float e2 = expf(v2 - v1);
        const float inv = 1.0f / (1.0f + e2);
        top_e[2 * t] = i1; top_e[2 * t + 1] = i2;
        top_w[2 * t] = inv; top_w[2 * t + 1] = e2 * inv;
    }
}

// ---------- kernel Cnt: LDS-privatized expert histogram ----------
__global__ __launch_bounds__(256) void kCnt(const int* __restrict__ top_e, int* __restrict__ counts) {
    __shared__ int lc[NE];
    const int tid = threadIdx.x;
    if (tid < NE) lc[tid] = 0;
    __syncthreads();
    const int t = blockIdx.x * 256 + tid;
    atomicAdd(&lc[top_e[2 * t]], 1);
    atomicAdd(&lc[top_e[2 * t + 1]], 1);
    __syncthreads();
    if (tid < NE) atomicAdd(&counts[tid], lc[tid]);
}

// ---------- kernel D: padded prefix sum over expert counts ----------
__global__ void kD(const int* __restrict__ counts, int* __restrict__ offsets) {
    if (threadIdx.x == 0) {
        int off = 0;
        for (int e = 0; e < NE; ++e) { offsets[e] = off; off += (counts[e] + 127) & ~127; }
        offsets[NE] = off;
    }
}

// ---------- kernel E: scatter token->row, block-aggregated ----------
__global__ __launch_bounds__(256) void kE(const int* __restrict__ top_e, const int* __restrict__ offsets,
                                          int* __restrict__ fill, int* __restrict__ rowtok,
                                          int* __restrict__ tok2row) {
    __shared__ int lc[NE], lbase[NE], lpos[NE];
    const int tid = threadIdx.x;
    if (tid < NE) { lc[tid] = 0; lpos[tid] = 0; }
    __syncthreads();
    const int t = blockIdx.x * 256 + tid;
    const int e0 = top_e[2 * t], e1 = top_e[2 * t + 1];
    atomicAdd(&lc[e0], 1);
    atomicAdd(&lc[e1], 1);
    __syncthreads();
    if (tid < NE) lbase[tid] = atomicAdd(&fill[tid], lc[tid]);
    __syncthreads();
    const int p0 = atomicAdd(&lpos[e0], 1);
    const int p1 = atomicAdd(&lpos[e1], 1);
    const int r0 = offsets[e0] + lbase[e0] + p0;
    const int r1 = offsets[e1] + lbase[e1] + p1;
    rowtok[r0] = t; rowtok[r1] = t;
    tok2row[2 * t] = r0; tok2row[2 * t + 1] = r1;
}

// ---------- kernel F: gather per-assignment A rows [hln | eemb(e)] ----------
__global__ __launch_bounds__(128) void kF(const unsigned short* __restrict__ hln,
                                          const unsigned short* __restrict__ eemb,
                                          const int* __restrict__ rowtok, const int* __restrict__ offsets,
                                          unsigned short* __restrict__ xin) {
    const int row = blockIdx.x;
    if (row >= offsets[NE]) return;
    const int tid = threadIdx.x;
    const int t = rowtok[row];
    uint4* dst = (uint4*)(xin + (size_t)row * KR);
    if (t < 0) {
        const uint4 z = {0u, 0u, 0u, 0u};
        dst[tid] = z;
        if (tid < 8) dst[128 + tid] = z;
    } else {
        int e = 0;
        while (row >= offsets[e + 1]) ++e;
        dst[tid] = ((const uint4*)(hln + (size_t)t * DMODEL))[tid];
        if (tid < 8) dst[128 + tid] = ((const uint4*)(eemb + ((size_t)t * NE + e) * DFE))[tid];
    }
}

// ---------- expert GEMM1: hh = gelu(xin @ We1[e] + be1[e]) ----------
// 128x256 tile, BK=64, 512 threads (8 waves, 2x4 wave grid), single-buffer LDS 48KB
// (3 blocks/CU): ~256 MFMA per block-iter against one 48KB staging round so
// inter-block overlap (m114) covers the ~900cyc HBM latency the barrier drains.
// LDS chunk XOR-swizzle (row&7) keeps reads conflict-free (R3: conflicts -> 0).
__global__ __launch_bounds__(512) void gemm1(const unsigned short* __restrict__ A,
                                             const unsigned short* __restrict__ BT,
                                             const float* __restrict__ be1,
                                             unsigned short* __restrict__ hh,
                                             const int* __restrict__ offsets) {
    const int m_base = blockIdx.y * 128;
    if (m_base >= offsets[NE]) return;
    int e = 0;
    while (m_base >= offsets[e + 1]) ++e;
    const int n_base = blockIdx.x * 256;
    __shared__ unsigned short As[128 * 64];
    __shared__ unsigned short Bs[256 * 64];
    const int tid = threadIdx.x, lane = tid & 63, wave = tid >> 6;
    const int wm = (wave & 1) * 64, wn = (wave >> 1) * 64;
    const int l16 = lane & 15, quad = lane >> 4;
    const int sw = l16 & 7;
    f32x4 acc[4][4];
#pragma unroll
    for (int mi = 0; mi < 4; ++mi)
#pragma unroll
        for (int ni = 0; ni < 4; ++ni) { acc[mi][ni].x = 0.f; acc[mi][ni].y = 0.f; acc[mi][ni].z = 0.f; acc[mi][ni].w = 0.f; }
    const unsigned short* Ap = A + (size_t)m_base * KR;
    const unsigned short* Bp = BT + ((size_t)e * DEH + n_base) * KR;
    for (int k0 = 0; k0 < KR; k0 += 64) {
#pragma unroll
        for (int i = 0; i < 2; ++i) {          // As: 128 rows x 8 chunks = 1024
            const int ch = i * 512 + tid;
            const int r = ch >> 3, c = (ch & 7) ^ (r & 7);
            GLLDS16(Ap + (size_t)r * KR + k0 + c * 8, As + (i * 512 + wave * 64) * 8);
        }
#pragma unroll
        for (int i = 0; i < 4; ++i) {          // Bs: 256 rows x 8 chunks = 2048
            const int ch = i * 512 + tid;
            const int r = ch >> 3, c = (ch & 7) ^ (r & 7);
            GLLDS16(Bp + (size_t)r * KR + k0 + c * 8, Bs + (i * 512 + wave * 64) * 8);
        }
        __syncthreads();
#pragma unroll
        for (int kc = 0; kc < 2; ++kc) {
            bf16x8 af[4], bfr[4];
#pragma unroll
            for (int mi = 0; mi < 4; ++mi)
                af[mi] = *(const bf16x8*)(As + (wm + mi * 16 + l16) * 64 + (((kc * 4 + quad) ^ sw) * 8));
#pragma unroll
            for (int ni = 0; ni < 4; ++ni)
                bfr[ni] = *(const bf16x8*)(Bs + (wn + ni * 16 + l16) * 64 + (((kc * 4 + quad) ^ sw) * 8));
#pragma unroll
            for (int mi = 0; mi < 4; ++mi)
#pragma unroll
                for (int ni = 0; ni < 4; ++ni)
                    acc[mi][ni] = __builtin_amdgcn_mfma_f32_16x16x32_bf16(af[mi], bfr[ni], acc[mi][ni], 0, 0, 0);
        }
        __syncthreads();
    }
#pragma unroll
    for (int ni = 0; ni < 4; ++ni) {
        const int col = n_base + wn + ni * 16 + l16;
        const float bias = be1[e * DEH + col];
#pragma unroll
        for (int mi = 0; mi < 4; ++mi) {
            const int row = m_base + wm + mi * 16 + quad * 4;
#pragma unroll
            for (int r = 0; r < 4; ++r) {
                const float v = acc[mi][ni][r] + bias;
                const float gl = v / (1.0f + __expf(-1.5957691216057308f * (v + 0.044715f * v * v * v)));
                hh[(size_t)(row + r) * DEH + col] = f2bf(gl);
            }
        }
    }
}

// ---------- expert GEMM2: eo = hh @ We2[e] + be2[e] (same 128x256 structure) ----------
__global__ __launch_bounds__(512) void gemm2(const unsigned short* __restrict__ A,
                                             const unsigned short* __restrict__ BT,
                                             const float* __restrict__ be2,
                                             unsigned short* __restrict__ eo,
                                             const int* __restrict__ offsets) {
    const int m_base = blockIdx.y * 128;
    if (m_base >= offsets[NE]) return;
    int e = 0;
    while (m_base >= offsets[e + 1]) ++e;
    const int n_base = blockIdx.x * 256;
    __shared__ unsigned short As[128 * 64];
    __shared__ unsigned short Bs[256 * 64];
    const int tid = threadIdx.x, lane = tid & 63, wave = tid >> 6;
    const int wm = (wave & 1) * 64, wn = (wave >> 1) * 64;
    const int l16 = lane & 15, quad = lane >> 4;
    const int sw = l16 & 7;
    f32x4 acc[4][4];
#pragma unroll
    for (int mi = 0; mi < 4; ++mi)
#pragma unroll
        for (int ni = 0; ni < 4; ++ni) { acc[mi][ni].x = 0.f; acc[mi][ni].y = 0.f; acc[mi][ni].z = 0.f; acc[mi][ni].w = 0.f; }
    const unsigned short* Ap = A + (size_t)m_base * DEH;
    const unsigned short* Bp = BT + ((size_t)e * DMODEL + n_base) * DEH;
    for (int k0 = 0; k0 < DEH; k0 += 64) {
#pragma unroll
        for (int i = 0; i < 2; ++i) {
            const int ch = i * 512 + tid;
            const int r = ch >> 3, c = (ch & 7) ^ (r & 7);
            GLLDS16(Ap + (size_t)r * DEH + k0 + c * 8, As + (i * 512 + wave * 64) * 8);
        }
#pragma unroll
        for (int i = 0; i < 4; ++i) {
            const int ch = i * 512 + tid;
            const int r = ch >> 3, c = (ch & 7) ^ (r & 7);
            GLLDS16(Bp + (size_t)r * DEH + k0 + c * 8, Bs + (i * 512 + wave * 64) * 8);
        }
        __syncthreads();
#pragma unroll
        for (int kc = 0; kc < 2; ++kc) {
            bf16x8 af[4], bfr[4];
#pragma unroll
            for (int mi = 0; mi < 4; ++mi)
                af[mi] = *(const bf16x8*)(As + (wm + mi * 16 + l16) * 64 + (((kc * 4 + quad) ^ sw) * 8));
#pragma unroll
            for (int ni = 0; ni < 4; ++ni)
                bfr[ni] = *(const bf16x8*)(Bs + (wn + ni * 16 + l16) * 64 + (((kc * 4 + quad) ^ sw) * 8));
#pragma unroll
            for (int mi = 0; mi < 4; ++mi)
#pragma unroll
                for (int ni = 0; ni < 4; ++ni)
                    acc[mi][ni] = __builtin_amdgcn_mfma_f32_16x16x32_bf16(af[mi], bfr[ni], acc[mi][ni], 0, 0, 0);
        }
        __syncthreads();
    }
#pragma unroll
    for (int ni = 0; ni < 4; ++ni) {
        const int col = n_base + wn + ni * 16 + l16;
        const float bias = be2[e * DMODEL + col];
#pragma unroll
        for (int mi = 0; mi < 4; ++mi) {
            const int row = m_base + wm + mi * 16 + quad * 4;
#pragma unroll
            for (int r = 0; r < 4; ++r)
                eo[(size_t)(row + r) * DMODEL + col] = f2bf(acc[mi][ni][r] + bias);
        }
    }
}

// ---------- combine: out = h + w0*eo[r0] + w1*eo[r1] ----------
__global__ __launch_bounds__(256) void kComb(const float* __restrict__ h, const unsigned short* __restrict__ eo,
                                             const int* __restrict__ tok2row, const float* __restrict__ top_w,
                                             float* __restrict__ out) {
    const int t = blockIdx.x, tid = threadIdx.x;
    const int r0 = tok2row[2 * t], r1 = tok2row[2 * t + 1];
    const float w0 = top_w[2 * t], w1 = top_w[2 * t + 1];
    const float4 hv = *(const float4*)(h + (size_t)t * DMODEL + tid * 4);
    const ushort4 a = *(const ushort4*)(eo + (size_t)r0 * DMODEL + tid * 4);
    const ushort4 b = *(const ushort4*)(eo + (size_t)r1 * DMODEL + tid * 4);
    float4 o;
    o.x = hv.x + w0 * bf2f(a.x) + w1 * bf2f(b.x);
    o.y = hv.y + w0 * bf2f(a.y) + w1 * bf2f(b.y);
    o.z = hv.z + w0 * bf2f(a.z) + w1 * bf2f(b.z);
    o.w = hv.w + w0 * bf2f(a.w) + w1 * bf2f(b.w);
    *(float4*)(out + (size_t)t * DMODEL + tid * 4) = o;
}

extern "C" void kernel_launch(void* const* d_in, const int* in_sizes, int n_in,
                              void* d_out, int out_size, void* d_ws, size_t ws_size,
                              hipStream_t stream) {
    const float* h    = (const float*)d_in[0];
    const float* feat = (const float*)d_in[1];
    const float* ln_g = (const float*)d_in[2];
    const float* ln_b = (const float*)d_in[3];
    const float* Wsf  = (const float*)d_in[4];
    const float* bsf  = (const float*)d_in[5];
    const float* Wr1  = (const float*)d_in[6];
    const float* br1  = (const float*)d_in[7];
    const float* Wr2  = (const float*)d_in[8];
    const float* br2  = (const float*)d_in[9];
    const float* Wef  = (const float*)d_in[10];
    const float* bef  = (const float*)d_in[11];
    const float* We1  = (const float*)d_in[12];
    const float* be1  = (const float*)d_in[13];
    const float* We2  = (const float*)d_in[14];
    const float* be2  = (const float*)d_in[15];
    const int* stage_idx  = (const int*)d_in[16];
    const int* expert_idx = (const int*)d_in[17];
    float* out = (float*)d_out;

    char* ws = (char*)d_ws;
    float*          rin  = (float*)(ws + 0);                       // 8192*1088*4  = 35651584
    unsigned short* hln  = (unsigned short*)(ws + 35651584);       // 8192*1024*2  = 16777216
    unsigned short* eemb = (unsigned short*)(ws + 52428800);       // 8192*8*64*2  = 8388608
    float*          hr   = (float*)(ws + 60817408);                // 8192*256*4   = 8388608
    unsigned short* hh   = (unsigned short*)(ws + 0);              // alias: 17408*2048*2 = 71303168
    unsigned short* xin  = (unsigned short*)(ws + 75497472);       // 17408*1088*2 = 37879808
    unsigned short* eo   = (unsigned short*)(ws + 75497472);       // alias: 17408*1024*2 = 35651584
    unsigned short* We1T = (unsigned short*)(ws + 113377280);      // 35651584
    unsigned short* We2T = (unsigned short*)(ws + 149028864);      // 33554432
    int*   top_e   = (int*)(ws + 182583296);
    float* top_w   = (float*)(ws + 182648832);
    int*   tok2row = (int*)(ws + 182714368);
    int*   rowtok  = (int*)(ws + 182779904);
    int*   counts  = (int*)(ws + 182849536);
    int*   fill    = (int*)(ws + 182849600);
    int*   offsets = (int*)(ws + 182849664);
    if (ws_size < 182849728) return;

    hipMemsetAsync(counts, 0, 128, stream);                  // counts + fill
    hipMemsetAsync(rowtok, 0xFF, MAXROWS * 4, stream);       // rowtok = -1

    kT<<<dim3(64, 34, 8), 256, 0, stream>>>(We1, We1T, KR, DEH);
    kT<<<dim3(32, 64, 8), 256, 0, stream>>>(We2, We2T, DEH, DMODEL);
    kA<<<T_TOK, 256, 0, stream>>>(h, feat, ln_g, ln_b, Wsf, bsf, Wef, bef,
                                  stage_idx, expert_idx, rin, hln, eemb);
    kB<<<dim3(DRH / 64, T_TOK / 64), 256, 0, stream>>>(rin, Wr1, br1, hr);
    kC<<<T_TOK / 4, 256, 0, stream>>>(hr, Wr2, br2, top_e, top_w);
    kCnt<<<T_TOK / 256, 256, 0, stream>>>(top_e, counts);
    kD<<<1, 64, 0, stream>>>(counts, offsets);
    kE<<<T_TOK / 256, 256, 0, stream>>>(top_e, offsets, fill, rowtok, tok2row);
    kF<<<MAXROWS, 128, 0, stream>>>(hln, eemb, rowtok, offsets, xin);
    gemm1<<<dim3(DEH / 256, MAXMT), 512, 0, stream>>>(xin, We1T, be1, hh, offsets);
    gemm2<<<dim3(DMODEL / 256, MAXMT), 512, 0, stream>>>(hh, We2T, be2, eo, offsets);
    kComb<<<T_TOK, 256, 0, stream>>>(h, eo, tok2row, top_w, out);
}